// Round 19
// baseline (554.478 us; speedup 1.0000x reference)
//
#include <hip/hip_runtime.h>
#include <hip/hip_bf16.h>

typedef unsigned short u16;
typedef unsigned int u32;
typedef __attribute__((ext_vector_type(8))) short bf16x8;
typedef __attribute__((ext_vector_type(4))) float f32x4;

constexpr int NH = 16;
constexpr int H = 2048;
constexpr float SCALE = 0.08838834764831845f;   // 1/sqrt(128)
constexpr float L2E = 1.4426950408889634f;      // log2(e)
constexpr float SCALE2 = SCALE * L2E;           // QK scale in log2 domain
constexpr float THR2 = 8.0f * L2E;              // defer-max threshold (log2 units)

__device__ __forceinline__ u16 f2bf(float f) {
    u32 u = __float_as_uint(f);
    u32 r = u + 0x7fffu + ((u >> 16) & 1u);   // RNE (finite inputs only)
    return (u16)(r >> 16);
}
__device__ __forceinline__ u32 pack2(float x, float y) {
    return (u32)f2bf(x) | ((u32)f2bf(y) << 16);
}
__device__ __forceinline__ u32 pack2_cvt(float x, float y) {
    __hip_bfloat162 h = __float22bfloat162_rn(float2{x, y});
    return *reinterpret_cast<u32*>(&h);
}

#define GLD_LDS16(gsrc, ldst)                                                  \
    __builtin_amdgcn_global_load_lds(                                          \
        (const __attribute__((address_space(1))) void*)(gsrc),                 \
        (__attribute__((address_space(3))) void*)(ldst), 16, 0, 0)

// ---------------- batched weight transpose + convert: f32[K][N] -> bf16[N][K] -------
__global__ __launch_bounds__(256)
void transpose_cvt4(const float* __restrict__ i0, const float* __restrict__ i1,
                    const float* __restrict__ i2, const float* __restrict__ i3,
                    u16* __restrict__ o0, u16* __restrict__ o1,
                    u16* __restrict__ o2, u16* __restrict__ o3, int K, int N) {
    const float* in = (blockIdx.z == 0) ? i0 : (blockIdx.z == 1) ? i1
                    : (blockIdx.z == 2) ? i2 : i3;
    u16* out = (blockIdx.z == 0) ? o0 : (blockIdx.z == 1) ? o1
             : (blockIdx.z == 2) ? o2 : o3;
    __shared__ u16 tile[32][33];
    int bn = blockIdx.x * 32, bk = blockIdx.y * 32;
    int tx = threadIdx.x & 31, ty = threadIdx.x >> 5;  // ty 0..7
#pragma unroll
    for (int r = 0; r < 32; r += 8)
        tile[tx][r + ty] = f2bf(in[(size_t)(bk + r + ty) * N + bn + tx]);
    __syncthreads();
#pragma unroll
    for (int r = 0; r < 32; r += 8)
        out[(size_t)(bn + r + ty) * K + bk + tx] = tile[r + ty][tx];
}

// ---------------- RMSNorm f32 -> bf16 (blocks >= nrows run a f32->bf16 cvt) --------
__global__ __launch_bounds__(256)
void rmsnorm_cvt(const float* __restrict__ x, const float* __restrict__ w,
                 u16* __restrict__ y, int nrows,
                 const float* __restrict__ ca, u16* __restrict__ coa,
                 const float* __restrict__ cb, u16* __restrict__ cob, int n4) {
    int blk = blockIdx.x;
    int t = threadIdx.x;
    if (blk >= nrows) {   // companion cvt slice (dsk/dsv), grid-stride
        int nb = gridDim.x - nrows;
        int stride = nb * 256;
        for (int i = (blk - nrows) * 256 + t; i < 2 * n4; i += stride) {
            const float* in;
            u16* out;
            int j = i;
            if (j < n4) { in = ca; out = coa; }
            else { j -= n4; in = cb; out = cob; }
            float4 v = reinterpret_cast<const float4*>(in)[j];
            uint2 o;
            o.x = pack2(v.x, v.y);
            o.y = pack2(v.z, v.w);
            reinterpret_cast<uint2*>(out)[j] = o;
        }
        return;
    }
    int r = blk;
    const float4* xr = reinterpret_cast<const float4*>(x + (size_t)r * H);
    float4 v0 = xr[t * 2], v1 = xr[t * 2 + 1];
    float ss = v0.x * v0.x + v0.y * v0.y + v0.z * v0.z + v0.w * v0.w
             + v1.x * v1.x + v1.y * v1.y + v1.z * v1.z + v1.w * v1.w;
#pragma unroll
    for (int d = 1; d < 64; d <<= 1) ss += __shfl_xor(ss, d);
    __shared__ float red[4];
    if ((t & 63) == 0) red[t >> 6] = ss;
    __syncthreads();
    float tot = red[0] + red[1] + red[2] + red[3];
    float rs = rsqrtf(tot * (1.0f / H) + 1e-6f);
    const float4* wr = reinterpret_cast<const float4*>(w);
    float4 w0 = wr[t * 2], w1 = wr[t * 2 + 1];
    uint4 o;
    o.x = pack2(v0.x * rs * w0.x, v0.y * rs * w0.y);
    o.y = pack2(v0.z * rs * w0.z, v0.w * rs * w0.w);
    o.z = pack2(v1.x * rs * w1.x, v1.y * rs * w1.y);
    o.w = pack2(v1.z * rs * w1.z, v1.w * rs * w1.w);
    reinterpret_cast<uint4*>(y + (size_t)r * H)[t] = o;
}

// ---------------- GEMM body v3: BK=64, double-buffered, swizzled LDS ----------------
// LDS is caller-provided (single buffer; As = smem[0..16384), Bs = smem[16384..)).
// MODE 0: bf16 C.  MODE 1: Cf = resid + sigmoid(gate)*acc (f32).
template <int MODE, int BN>
__device__ __forceinline__
void gemm_body(u16* __restrict__ smem,
               const u16* __restrict__ A, const u16* __restrict__ Bt,
               u16* __restrict__ Cb, float* __restrict__ Cf,
               const float* __restrict__ resid, const float* __restrict__ gate_p,
               int N, int K, int brow, int bcol) {
    constexpr int WN = BN / 32;          // N frags per wave: 4 or 2
    constexpr int BWROWS = BN / 4;       // B rows staged per wave: 32 or 16
    u16* Asb = smem;                     // 2 x 128*64
    u16* Bsb = smem + 2 * 128 * 64;      // 2 x BN*64
    const int t = threadIdx.x;
    const int lane = t & 63, wid = t >> 6;
    const int wm = wid >> 1, wn = wid & 1;
    const int l15 = lane & 15, hi = lane >> 4;
    const int rsw = l15 & 7;

    f32x4 acc[4][WN] = {};
    const int srow = lane >> 3;
    const int sseg = ((lane & 7) ^ srow) * 8;
    const u16* aBase = A + (size_t)(brow + wid * 32 + srow) * K + sseg;
    const u16* bBase = Bt + (size_t)(bcol + wid * BWROWS + srow) * K + sseg;

#define GSTAGE(KT, BF)                                                          \
    do {                                                                        \
        _Pragma("unroll")                                                       \
        for (int u = 0; u < 4; ++u)                                             \
            GLD_LDS16(aBase + (size_t)(u * 8) * K + (KT),                       \
                      Asb + (BF) * 8192 + (wid * 32 + u * 8) * 64);             \
        _Pragma("unroll")                                                       \
        for (int u = 0; u < BWROWS / 8; ++u)                                    \
            GLD_LDS16(bBase + (size_t)(u * 8) * K + (KT),                       \
                      Bsb + (BF) * (BN * 64) + (wid * BWROWS + u * 8) * 64);    \
    } while (0)

    GSTAGE(0, 0);
    __syncthreads();
    int buf = 0;
    for (int kt = 0; kt < K; kt += 64) {
        if (kt + 64 < K) GSTAGE(kt + 64, buf ^ 1);
        const u16* as = Asb + buf * 8192;
        const u16* bs = Bsb + buf * (BN * 64);
        bf16x8 af[4][2], bfr[WN][2];
#pragma unroll
        for (int i = 0; i < 4; ++i) {
            int row = wm * 64 + i * 16 + l15;
#pragma unroll
            for (int ko = 0; ko < 2; ++ko)
                af[i][ko] = *reinterpret_cast<const bf16x8*>(
                    &as[row * 64 + (((ko * 4 + hi) ^ rsw) * 8)]);
        }
#pragma unroll
        for (int j = 0; j < WN; ++j) {
            int row = wn * (BN / 2) + j * 16 + l15;
#pragma unroll
            for (int ko = 0; ko < 2; ++ko)
                bfr[j][ko] = *reinterpret_cast<const bf16x8*>(
                    &bs[row * 64 + (((ko * 4 + hi) ^ rsw) * 8)]);
        }
#pragma unroll
        for (int ko = 0; ko < 2; ++ko)
#pragma unroll
            for (int i = 0; i < 4; ++i)
#pragma unroll
                for (int j = 0; j < WN; ++j)
                    acc[i][j] = __builtin_amdgcn_mfma_f32_16x16x32_bf16(
                        af[i][ko], bfr[j][ko], acc[i][j], 0, 0, 0);
        __syncthreads();
        buf ^= 1;
    }
#undef GSTAGE

    float g = 0.f;
    if (MODE == 1) g = 1.0f / (1.0f + expf(-gate_p[0]));
    const int r0 = hi * 4, c0 = l15;
#pragma unroll
    for (int i = 0; i < 4; ++i) {
#pragma unroll
        for (int j = 0; j < WN; ++j) {
            int col = bcol + wn * (BN / 2) + j * 16 + c0;
#pragma unroll
            for (int r = 0; r < 4; ++r) {
                int row = brow + wm * 64 + i * 16 + r0 + r;
                float v = acc[i][j][r];
                if (MODE == 0) Cb[(size_t)row * N + col] = f2bf(v);
                else Cf[(size_t)row * N + col] = resid[(size_t)row * N + col] + g * v;
            }
        }
    }
}

template <int MODE, int BN>
__global__ __launch_bounds__(256)
void gemm_tn(const u16* __restrict__ A, const u16* __restrict__ Bt,
             u16* __restrict__ Cb, float* __restrict__ Cf,
             const float* __restrict__ resid, const float* __restrict__ gate_p,
             int M, int N, int K) {
    __shared__ u16 smem[16384 + BN * 128];
    int nbx = gridDim.x;
    int nwg = nbx * gridDim.y;
    int lin = blockIdx.y * nbx + blockIdx.x;
    if (!(nwg & 7)) { int q = nwg >> 3; lin = (lin & 7) * q + (lin >> 3); }
    gemm_body<MODE, BN>(smem, A, Bt, Cb, Cf, resid, gate_p, N, K,
                        (lin / nbx) * 128, (lin % nbx) * BN);
}

// GEMM with a z=1 companion slice running a grid-stride f32->bf16 convert
template <int MODE, int BN>
__global__ __launch_bounds__(256)
void gemm_tn_cvt(const u16* __restrict__ A, const u16* __restrict__ Bt,
                 u16* __restrict__ Cb, float* __restrict__ Cf,
                 const float* __restrict__ resid, const float* __restrict__ gate_p,
                 int M, int N, int K,
                 const float* __restrict__ ca, u16* __restrict__ coa,
                 const float* __restrict__ cb2, u16* __restrict__ cob, int n4) {
    __shared__ u16 smem[16384 + BN * 128];
    if (blockIdx.z == 1) {
        int nblk = gridDim.x * gridDim.y;
        int stride = nblk * 256;
        for (int i = (blockIdx.y * gridDim.x + blockIdx.x) * 256 + threadIdx.x;
             i < 2 * n4; i += stride) {
            const float* in;
            u16* out;
            int j = i;
            if (j < n4) { in = ca; out = coa; }
            else { j -= n4; in = cb2; out = cob; }
            float4 v = reinterpret_cast<const float4*>(in)[j];
            uint2 o;
            o.x = pack2(v.x, v.y);
            o.y = pack2(v.z, v.w);
            reinterpret_cast<uint2*>(out)[j] = o;
        }
        return;
    }
    int nbx = gridDim.x;
    int nwg = nbx * gridDim.y;
    int lin = blockIdx.y * nbx + blockIdx.x;
    if (!(nwg & 7)) { int q = nwg >> 3; lin = (lin & 7) * q + (lin >> 3); }
    gemm_body<MODE, BN>(smem, A, Bt, Cb, Cf, resid, gate_p, N, K,
                        (lin / nbx) * 128, (lin % nbx) * BN);
}

// dual-problem wrapper (kc/vc fused): blockIdx.z selects the pointer set
template <int MODE, int BN>
__global__ __launch_bounds__(256)
void gemm_tn_z2(const u16* __restrict__ A0, const u16* __restrict__ B0, u16* __restrict__ C0,
                const u16* __restrict__ A1, const u16* __restrict__ B1, u16* __restrict__ C1,
                int N, int K) {
    __shared__ u16 smem[16384 + BN * 128];
    const u16* A = blockIdx.z ? A1 : A0;
    const u16* B = blockIdx.z ? B1 : B0;
    u16* C = blockIdx.z ? C1 : C0;
    gemm_body<MODE, BN>(smem, A, B, C, nullptr, nullptr, nullptr, N, K,
                        blockIdx.y * 128, blockIdx.x * BN);
}

// triple co-schedule: fq INTERLEAVED with fk + vT (r18 win: -21us)
__global__ __launch_bounds__(256)
void gemm_triple(const u16* __restrict__ Aq, const u16* __restrict__ Bq,
                 u16* __restrict__ Cq,
                 const u16* __restrict__ Ak, const u16* __restrict__ Bk,
                 u16* __restrict__ Ck,
                 const u16* __restrict__ Av, const u16* __restrict__ Bv,
                 u16* __restrict__ Cv, int K) {
    __shared__ u16 smem[32768];   // 64 KB: max(BN=128 layout)
    int lin = blockIdx.x;         // 0..1023
    if (!(lin & 1)) {
        int l = lin >> 1;         // 0..511, fq: M=4096 N=2048 nbx=16
        int q = 512 >> 3;
        l = (l & 7) * q + (l >> 3);
        gemm_body<0, 128>(smem, Aq, Bq, Cq, nullptr, nullptr, nullptr, 2048, K,
                          (l / 16) * 128, (l % 16) * 128);
    } else {
        int j = lin >> 1;         // 0..511
        if (j < 256) {            // fk: M=4096 N=512 nbx=8
            int q = 256 >> 3;
            j = (j & 7) * q + (j >> 3);
            gemm_body<0, 64>(smem, Ak, Bk, Ck, nullptr, nullptr, nullptr, 512, K,
                             (j / 8) * 128, (j % 8) * 64);
        } else {                  // vT: M=512 N=4096 nbx=64
            j -= 256;
            int q = 256 >> 3;
            j = (j & 7) * q + (j >> 3);
            gemm_body<0, 64>(smem, Av, Bv, Cv, nullptr, nullptr, nullptr, 4096, K,
                             (j / 64) * 128, (j % 64) * 64);
        }
    }
}

// ---------------- coarse attention (ND=64 keys, exact softmax, exp2 domain) --------
__global__ __launch_bounds__(256)
void coarse_attn(const u16* __restrict__ q, const u16* __restrict__ kc,
                 const u16* __restrict__ vc, const float* __restrict__ mask,
                 float* __restrict__ doc_part, u16* __restrict__ attn_c) {
    constexpr int SC = 2048 / 64;
    int bid = blockIdx.x;
    int b = bid / (NH * SC);
    int rem = bid % (NH * SC);
    int h = rem / SC, sc = rem % SC;
    int kv = h >> 2;
    int t = threadIdx.x, lane = t & 63, wid = t >> 6;
    const int l15 = lane & 15, k0 = (lane >> 4) * 8;

    __shared__ u16 Kt[64 * 136];
    __shared__ u16 Vt[128 * 72];
    __shared__ u16 Pt[4][16 * 72];
    __shared__ float p_acc[64];

    {   // stage K [64 keys][128 d]
        int n = t >> 2, s2 = t & 3;
        const u16* src = kc + (size_t)(b * 64 + n) * 512 + kv * 128;
#pragma unroll
        for (int u = 0; u < 4; ++u) {
            int sg = s2 + u * 4;
            *reinterpret_cast<uint4*>(&Kt[n * 136 + sg * 8]) =
                *reinterpret_cast<const uint4*>(src + sg * 8);
        }
    }
    {   // stage V transposed: Vt[d][key]
        int n = t & 63, dblk = t >> 6;
        const u16* src = vc + (size_t)(b * 64 + n) * 512 + kv * 128 + dblk * 32;
#pragma unroll
        for (int u = 0; u < 4; ++u) {
            u16 tmp[8];
            *reinterpret_cast<uint4*>(tmp) = *reinterpret_cast<const uint4*>(src + u * 8);
#pragma unroll
            for (int e = 0; e < 8; ++e) Vt[(dblk * 32 + u * 8 + e) * 72 + n] = tmp[e];
        }
    }
    if (t < 64) p_acc[t] = 0.f;
    __syncthreads();

    int qrow = sc * 64 + wid * 16 + l15;
    const u16* qsrc = q + (size_t)(b * 2048 + qrow) * 2048 + h * 128;
    bf16x8 af[4];
#pragma unroll
    for (int kk = 0; kk < 4; ++kk)
        af[kk] = *reinterpret_cast<const bf16x8*>(qsrc + kk * 32 + k0);

    f32x4 sc4[4] = {};
#pragma unroll
    for (int kk = 0; kk < 4; ++kk)
#pragma unroll
        for (int j = 0; j < 4; ++j) {
            bf16x8 bfr = *reinterpret_cast<const bf16x8*>(&Kt[(j * 16 + l15) * 136 + kk * 32 + k0]);
            sc4[j] = __builtin_amdgcn_mfma_f32_16x16x32_bf16(af[kk], bfr, sc4[j], 0, 0, 0);
        }

    float s[4][4];
#pragma unroll
    for (int j = 0; j < 4; ++j) {
        float bia = (1.0f - mask[b * 64 + j * 16 + l15]) * (-1e9f * L2E);
#pragma unroll
        for (int r = 0; r < 4; ++r) s[j][r] = sc4[j][r] * SCALE2 + bia;
    }
    float m4[4], l4[4];
#pragma unroll
    for (int r = 0; r < 4; ++r) {
        float m = fmaxf(fmaxf(s[0][r], s[1][r]), fmaxf(s[2][r], s[3][r]));
#pragma unroll
        for (int d = 1; d < 16; d <<= 1) m = fmaxf(m, __shfl_xor(m, d));
        m4[r] = m;
    }
#pragma unroll
    for (int r = 0; r < 4; ++r) {
        float l = 0.f;
#pragma unroll
        for (int j = 0; j < 4; ++j) { s[j][r] = exp2f(s[j][r] - m4[r]); l += s[j][r]; }
#pragma unroll
        for (int d = 1; d < 16; d <<= 1) l += __shfl_xor(l, d);
        l4[r] = l;
    }
#pragma unroll
    for (int j = 0; j < 4; ++j) {
        float cs = 0.f;
#pragma unroll
        for (int r = 0; r < 4; ++r) {
            float pr = s[j][r] / l4[r];
            Pt[wid][((lane >> 4) * 4 + r) * 72 + j * 16 + l15] = f2bf(pr);
            cs += pr;
        }
        cs += __shfl_xor(cs, 16);
        cs += __shfl_xor(cs, 32);
        if (lane < 16) atomicAdd(&p_acc[j * 16 + lane], cs);
    }
    __syncthreads();

    f32x4 o4[8] = {};
#pragma unroll
    for (int kk2 = 0; kk2 < 2; ++kk2) {
        bf16x8 a2 = *reinterpret_cast<const bf16x8*>(&Pt[wid][l15 * 72 + kk2 * 32 + k0]);
#pragma unroll
        for (int j2 = 0; j2 < 8; ++j2) {
            bf16x8 b2 = *reinterpret_cast<const bf16x8*>(&Vt[(j2 * 16 + l15) * 72 + kk2 * 32 + k0]);
            o4[j2] = __builtin_amdgcn_mfma_f32_16x16x32_bf16(a2, b2, o4[j2], 0, 0, 0);
        }
    }
#pragma unroll
    for (int j2 = 0; j2 < 8; ++j2)
#pragma unroll
        for (int r = 0; r < 4; ++r) {
            int row = sc * 64 + wid * 16 + (lane >> 4) * 4 + r;
            attn_c[(size_t)(b * 2048 + row) * 2048 + h * 128 + j2 * 16 + l15] = f2bf(o4[j2][r]);
        }
    if (t < 64) atomicAdd(&doc_part[(blockIdx.x & 7) * 128 + b * 64 + t], p_acc[t]);
}

// ---------------- fine bias (doc-score finalize fused; bias pre-scaled by log2e) ----
__global__ __launch_bounds__(256)
void bias_kernel(const float* __restrict__ doc_part, const int* __restrict__ map,
                 const float* __restrict__ tmask, float* __restrict__ bias) {
    __shared__ float lg[128];
    int t = threadIdx.x;
    if (t < 128) {
        float s = 0.f;
#pragma unroll
        for (int i = 0; i < 8; ++i) s += doc_part[i * 128 + t];
        lg[t] = logf(s / 32768.0f + 1e-6f);
    }
    __syncthreads();
    int i = blockIdx.x * 256 + t;
    if (i >= 2 * 2048) return;
    int b = i >> 11;
    bias[i] = (lg[b * 64 + map[i]] + (1.0f - tmask[i]) * -1e9f) * L2E;
}

// ---------------- fine flash attention v9: KVBLK=32 dbuf, NO split ----------------
// The untested quadrant: 40 KB LDS -> 4 blocks/CU = 16 waves/CU (2x TLP vs
// r13's 80KB/2-block version) while keeping the no-split access pattern whose
// FETCH is clean (~42 MB; each KV slice shared by 16 time-correlated blocks,
// consecutive 32-key tiles touch adjacent halves of the same 128B V lines ->
// L2 absorbs). KVBLK=32 staging/swizzles are the r10/r11-verified pieces.
__global__ __launch_bounds__(256, 4)
void flash_attn(const u16* __restrict__ q, const u16* __restrict__ kf,
                const u16* __restrict__ vT, const float* __restrict__ bias,
                u16* __restrict__ attn_f) {
    int bid = blockIdx.x;
    int b = bid >> 8;              // NH * 16 = 256 blocks per batch
    int rem = bid & 255;
    int h = rem >> 4, sc = rem & 15;
    int kv = h >> 2;
    int t = threadIdx.x, lane = t & 63, wid = t >> 6;
    const int l15 = lane & 15, hi = lane >> 4;
    const int k0 = hi * 8;
    const int psw = (l15 >> 1) & 3;      // P row swizzle

    __shared__ u16 Kt[2][32 * 128];    // [key][d], swizzled 16B slots (16 KB)
    __shared__ u16 Vt[2][128 * 32];    // [d][key], swizzled 16B slots (16 KB)
    __shared__ u16 Pt[4][32 * 32];     // per-wave P[q][key], swizzled (8 KB)

    // Q fragments: 2 q-frags of 16 rows each
    bf16x8 qf4[2][4];
#pragma unroll
    for (int f = 0; f < 2; ++f) {
        int qrow = sc * 128 + wid * 32 + f * 16 + l15;
        const u16* qsrc = q + (size_t)(b * 2048 + qrow) * 2048 + h * 128;
#pragma unroll
        for (int kk = 0; kk < 4; ++kk)
            qf4[f][kk] = *reinterpret_cast<const bf16x8*>(qsrc + kk * 32 + k0);
    }

    // staging lane roles (r10/r11-verified)
    const int krl = lane >> 4, kslot = lane & 15;   // K: 4 rows x 16 slots per 1KB
    const int vrl = lane >> 2, vslot = lane & 3;    // V: 16 rows x 4 slots per 1KB
    const u16* kbase = kf + (size_t)(b * 2048) * 512 + kv * 128;
    const u16* vbase = vT + (size_t)(kv * 128) * 4096 + b * 2048;
    const float* bbase = bias + b * 2048;

#define STAGE_K(TT, BF)                                                            \
    do {                                                                           \
        _Pragma("unroll")                                                          \
        for (int u = 0; u < 2; ++u) {                                              \
            int row = wid * 8 + u * 4 + krl;                                       \
            const u16* src = kbase + (size_t)((TT) + row) * 512                    \
                             + ((kslot ^ (row & 7)) * 8);                          \
            GLD_LDS16(src, &Kt[BF][(wid * 8 + u * 4) * 128]);                      \
        }                                                                          \
    } while (0)
#define STAGE_V(TT, BF)                                                            \
    do {                                                                           \
        _Pragma("unroll")                                                          \
        for (int u = 0; u < 2; ++u) {                                              \
            int row = wid * 32 + u * 16 + vrl;                                     \
            const u16* src = vbase + (size_t)row * 4096 + (TT)                     \
                             + ((vslot ^ (row & 3)) * 8);                          \
            GLD_LDS16(src, &Vt[BF][(wid * 32 + u * 16) * 32]);                     \
        }                                                                          \
    } while (0)

    float mstate[2] = {-1e30f, -1e30f}, lstate[2] = {0.f, 0.f};   // log2 domain
    f32x4 o4[2][8] = {};

    STAGE_K(0, 0);
    STAGE_V(0, 0);
    __syncthreads();
    int par = 0;

    for (int t0 = 0; t0 < 2048; t0 += 32) {
        int t1 = (t0 + 32) & 2047;          // wrap-around prefetch
        STAGE_K(t1, par ^ 1);
        STAGE_V(t1, par ^ 1);

        // QK^T swapped: S^T[key][q]; each K-frag feeds 2 MFMAs
        f32x4 st0[2] = {}, st1[2] = {};
        __builtin_amdgcn_s_setprio(1);
#pragma unroll
        for (int kk = 0; kk < 4; ++kk)
#pragma unroll
            for (int kb = 0; kb < 2; ++kb) {
                int row = kb * 16 + l15;
                bf16x8 kfrag = *reinterpret_cast<const bf16x8*>(
                    &Kt[par][row * 128 + (((kk * 4 + hi) ^ (row & 7)) * 8)]);
                st0[kb] = __builtin_amdgcn_mfma_f32_16x16x32_bf16(kfrag, qf4[0][kk], st0[kb], 0, 0, 0);
                st1[kb] = __builtin_amdgcn_mfma_f32_16x16x32_bf16(kfrag, qf4[1][kk], st1[kb], 0, 0, 0);
            }
        __builtin_amdgcn_s_setprio(0);

        // per-lane: q = f*16 + l15, keys = kb*16 + hi*4 + r ; log2 domain
        float p[2][2][4];
        float pmax[2] = {-1e30f, -1e30f};
#pragma unroll
        for (int kb = 0; kb < 2; ++kb) {
            float4 b4 = *reinterpret_cast<const float4*>(bbase + t0 + kb * 16 + hi * 4);
            float bb[4] = {b4.x, b4.y, b4.z, b4.w};
#pragma unroll
            for (int r = 0; r < 4; ++r) {
                float v0 = st0[kb][r] * SCALE2 + bb[r];
                float v1 = st1[kb][r] * SCALE2 + bb[r];
                p[0][kb][r] = v0;
                p[1][kb][r] = v1;
                pmax[0] = fmaxf(pmax[0], v0);
                pmax[1] = fmaxf(pmax[1], v1);
            }
        }
#pragma unroll
        for (int f = 0; f < 2; ++f) {
            pmax[f] = fmaxf(pmax[f], __shfl_xor(pmax[f], 16));
            pmax[f] = fmaxf(pmax[f], __shfl_xor(pmax[f], 32));
        }

        // defer-max (T13): combined branch
        bool need = (pmax[0] > mstate[0] + THR2) || (pmax[1] > mstate[1] + THR2);
        if (__any(need)) {
#pragma unroll
            for (int f = 0; f < 2; ++f) {
                float mnew = fmaxf(mstate[f], pmax[f]);
                float sco = exp2f(mstate[f] - mnew);
                float sco_out[4];
#pragma unroll
                for (int r = 0; r < 4; ++r) sco_out[r] = __shfl(sco, hi * 4 + r);
#pragma unroll
                for (int j2 = 0; j2 < 8; ++j2)
#pragma unroll
                    for (int r = 0; r < 4; ++r) o4[f][j2][r] *= sco_out[r];
                lstate[f] *= sco;
                mstate[f] = mnew;
            }
        }

#pragma unroll
        for (int f = 0; f < 2; ++f) {
            float lt = 0.f;
#pragma unroll
            for (int kb = 0; kb < 2; ++kb)
#pragma unroll
                for (int r = 0; r < 4; ++r) {
                    p[f][kb][r] = exp2f(p[f][kb][r] - mstate[f]);
                    lt += p[f][kb][r];
                }
            lt += __shfl_xor(lt, 16);
            lt += __shfl_xor(lt, 32);
            lstate[f] += lt;
        }

        // write P[q][key] (per-wave, swizzled; same-wave DS ordering covers RAW)
#pragma unroll
        for (int f = 0; f < 2; ++f)
#pragma unroll
            for (int kb = 0; kb < 2; ++kb) {
                uint2 w;
                w.x = pack2_cvt(p[f][kb][0], p[f][kb][1]);
                w.y = pack2_cvt(p[f][kb][2], p[f][kb][3]);
                int idx = (f * 16 + l15) * 32
                        + (((kb * 2 + (hi >> 1)) ^ psw) * 8) + (hi & 1) * 4;
                *reinterpret_cast<uint2*>(&Pt[wid][idx]) = w;
            }

        // PV: O[q][d] += P (A) x V^T-frag (B)
        __builtin_amdgcn_s_setprio(1);
        bf16x8 pa0 = *reinterpret_cast<const bf16x8*>(
            &Pt[wid][l15 * 32 + ((hi ^ psw) * 8)]);
        bf16x8 pa1 = *reinterpret_cast<const bf16x8*>(
            &Pt[wid][(16 + l15) * 32 + ((hi ^ psw) * 8)]);
#pragma unroll
        for (int j2 = 0; j2 < 8; ++j2) {
            int d = j2 * 16 + l15;
            bf16x8 vb = *reinterpret_cast<const bf16x8*>(
                &Vt[par][d * 32 + ((hi ^ ((d >> 1) & 3)) * 8)]);
            o4[0][j2] = __builtin_amdgcn_mfma_f32_16x16x32_bf16(pa0, vb, o4[0][j2], 0, 0, 0);
            o4[1][j2] = __builtin_amdgcn_mfma_f32_16x16x32_bf16(pa1, vb, o4[1][j2], 0, 0, 0);
        }
        __builtin_amdgcn_s_setprio(0);
        __syncthreads();   // single drain point per tile
        par ^= 1;
    }
#undef STAGE_K
#undef STAGE_V

    // l is in softmax layout (q = l15 per frag); outputs need q = hi*4+r
#pragma unroll
    for (int f = 0; f < 2; ++f) {
        float linv[4];
#pragma unroll
        for (int r = 0; r < 4; ++r) linv[r] = 1.0f / __shfl(lstate[f], hi * 4 + r);
#pragma unroll
        for (int j2 = 0; j2 < 8; ++j2)
#pragma unroll
            for (int r = 0; r < 4; ++r) {
                int row = sc * 128 + wid * 32 + f * 16 + hi * 4 + r;
                attn_f[(size_t)(b * 2048 + row) * 2048 + h * 128 + j2 * 16 + l15] =
                    f2bf(o4[f][j2][r] * linv[r]);
            }
    }
}

// ---------------- launch ----------------
extern "C" void kernel_launch(void* const* d_in, const int* in_sizes, int n_in,
                              void* d_out, int out_size, void* d_ws, size_t ws_size,
                              hipStream_t stream) {
    const float* hidden = (const float*)d_in[0];
    const float* dsk    = (const float*)d_in[1];
    const float* dsv    = (const float*)d_in[2];
    const float* dsmask = (const float*)d_in[3];
    const float* tk     = (const float*)d_in[4];
    const float* tv     = (const float*)d_in[5];
    const float* tmask  = (const float*)d_in[6];
    const float* cn_w   = (const float*)d_in[7];
    const float* cq_w   = (const float*)d_in[8];
    const float* ck_w   = (const float*)d_in[9];
    const float* cv_w   = (const float*)d_in[10];
    const float* co_w   = (const float*)d_in[11];
    const float* c_gate = (const float*)d_in[12];
    const float* fn_w   = (const float*)d_in[13];
    const float* fq_w   = (const float*)d_in[14];
    const float* fk_w   = (const float*)d_in[15];
    const float* fv_w   = (const float*)d_in[16];
    const float* fo_w   = (const float*)d_in[17];
    const float* f_gate = (const float*)d_in[18];
    const int*   map    = (const int*)d_in[19];
    float* out_f = (float*)d_out;   // also the f32 buffer for coarse residual

    char* ws = (char*)d_ws;
    size_t off = 0;
    auto alloc = [&](size_t bytes) {
        char* p = ws + off;
        off += (bytes + 255) & ~(size_t)255;
        return p;
    };
    u16*  normA = (u16*)alloc(4096ULL * 2048 * 2);
    u16*  qbuf  = (u16*)alloc(4096ULL * 2048 * 2);
    u16*  kc    = (u16*)alloc(128ULL * 512 * 2);
    u16*  vc    = (u16*)alloc(128ULL * 512 * 2);
    u16*  kfb   = (u16*)alloc(4096ULL * 512 * 2);
    u16*  vTb   = (u16*)alloc(512ULL * 4096 * 2);   // V^T [kv*128+d][b*2048+t]
    u16*  tkb   = (u16*)alloc(4096ULL * 2048 * 2);
    u16*  tvb   = (u16*)alloc(4096ULL * 2048 * 2);
    u16*  dskb  = (u16*)alloc(128ULL * 2048 * 2);
    u16*  dsvb  = (u16*)alloc(128ULL * 2048 * 2);
    u16*  cqT   = (u16*)alloc(2048ULL * 2048 * 2);
    u16*  ckT   = (u16*)alloc(512ULL * 2048 * 2);
    u16*  cvT   = (u16*)alloc(512ULL * 2048 * 2);
    u16*  coT   = (u16*)alloc(2048ULL * 2048 * 2);
    u16*  fqT   = (u16*)alloc(2048ULL * 2048 * 2);
    u16*  fkT   = (u16*)alloc(512ULL * 2048 * 2);
    u16*  fvT   = (u16*)alloc(512ULL * 2048 * 2);
    u16*  foT   = (u16*)alloc(2048ULL * 2048 * 2);
    float* doc_part = (float*)alloc(8 * 128 * 4);
    float* biasb    = (float*)alloc(4096 * 4);

    hipMemsetAsync(doc_part, 0, 8 * 128 * 4, stream);

    // weight transposes, batched
    transpose_cvt4<<<dim3(64, 64, 4), 256, 0, stream>>>(cq_w, co_w, fq_w, fo_w,
                                                        cqT, coT, fqT, foT, 2048, 2048);
    transpose_cvt4<<<dim3(16, 64, 4), 256, 0, stream>>>(ck_w, cv_w, fk_w, fv_w,
                                                        ckT, cvT, fkT, fvT, 2048, 512);

    // coarse rmsnorm + co-scheduled dsk/dsv f32->bf16 convert (256 extra blocks)
    rmsnorm_cvt<<<4096 + 256, 256, 0, stream>>>(hidden, cn_w, normA, 4096,
                                                dsk, dskb, dsv, dsvb, 128 * 2048 / 4);

    // coarse q-projection + co-scheduled tk/tv f32->bf16 convert (z=1 slice)
    gemm_tn_cvt<0, 128><<<dim3(16, 32, 2), 256, 0, stream>>>(
        normA, cqT, qbuf, nullptr, nullptr, nullptr, 4096, 2048, 2048,
        tk, tkb, tv, tvb, 4096 * 2048 / 4);
    gemm_tn_z2<0, 64><<<dim3(8, 1, 2), 256, 0, stream>>>(dskb, ckT, kc, dsvb, cvT, vc, 512, 2048);

    // coarse attention (attn_c into normA) + doc-score partials
    coarse_attn<<<1024, 256, 0, stream>>>(qbuf, kc, vc, dsmask, doc_part, normA);
    bias_kernel<<<16, 256, 0, stream>>>(doc_part, map, tmask, biasb);

    // coarse o-proj + residual + gate -> d_out (f32)
    gemm_tn<1, 128><<<dim3(16, 32), 256, 0, stream>>>(normA, coT, nullptr, out_f, hidden, c_gate, 4096, 2048, 2048);

    // fine stage
    rmsnorm_cvt<<<4096, 256, 0, stream>>>(out_f, fn_w, qbuf, 4096,
                                          nullptr, nullptr, nullptr, nullptr, 0);
    // fq + fk + vT co-scheduled (interleaved blocks, shared 64 KB LDS union)
    gemm_triple<<<1024, 256, 0, stream>>>(qbuf, fqT, normA,
                                          tkb, fkT, kfb,
                                          fvT, tvb, vTb, 2048);

    flash_attn<<<512, 256, 0, stream>>>(normA, kfb, vTb, biasb, qbuf);

    // final o-proj + residual + gate -> d_out
    gemm_tn<1, 128><<<dim3(16, 32), 256, 0, stream>>>(qbuf, foT, nullptr, out_f, out_f, f_gate, 4096, 2048, 2048);
}

// Round 20
// 417.083 us; speedup vs baseline: 1.3294x; 1.3294x over previous
//
#include <hip/hip_runtime.h>
#include <hip/hip_bf16.h>

typedef unsigned short u16;
typedef unsigned int u32;
typedef __attribute__((ext_vector_type(8))) short bf16x8;
typedef __attribute__((ext_vector_type(4))) float f32x4;

constexpr int NH = 16;
constexpr int H = 2048;
constexpr float SCALE = 0.08838834764831845f;   // 1/sqrt(128)
constexpr float L2E = 1.4426950408889634f;      // log2(e)
constexpr float SCALE2 = SCALE * L2E;           // QK scale in log2 domain
constexpr float THR2 = 8.0f * L2E;              // defer-max threshold (log2 units)

__device__ __forceinline__ u16 f2bf(float f) {
    u32 u = __float_as_uint(f);
    u32 r = u + 0x7fffu + ((u >> 16) & 1u);   // RNE (finite inputs only)
    return (u16)(r >> 16);
}
__device__ __forceinline__ u32 pack2(float x, float y) {
    return (u32)f2bf(x) | ((u32)f2bf(y) << 16);
}
__device__ __forceinline__ u32 pack2_cvt(float x, float y) {
    __hip_bfloat162 h = __float22bfloat162_rn(float2{x, y});
    return *reinterpret_cast<u32*>(&h);
}

#define GLD_LDS16(gsrc, ldst)                                                  \
    __builtin_amdgcn_global_load_lds(                                          \
        (const __attribute__((address_space(1))) void*)(gsrc),                 \
        (__attribute__((address_space(3))) void*)(ldst), 16, 0, 0)

// ---------------- batched weight transpose + convert: f32[K][N] -> bf16[N][K] -------
__global__ __launch_bounds__(256)
void transpose_cvt4(const float* __restrict__ i0, const float* __restrict__ i1,
                    const float* __restrict__ i2, const float* __restrict__ i3,
                    u16* __restrict__ o0, u16* __restrict__ o1,
                    u16* __restrict__ o2, u16* __restrict__ o3, int K, int N) {
    const float* in = (blockIdx.z == 0) ? i0 : (blockIdx.z == 1) ? i1
                    : (blockIdx.z == 2) ? i2 : i3;
    u16* out = (blockIdx.z == 0) ? o0 : (blockIdx.z == 1) ? o1
             : (blockIdx.z == 2) ? o2 : o3;
    __shared__ u16 tile[32][33];
    int bn = blockIdx.x * 32, bk = blockIdx.y * 32;
    int tx = threadIdx.x & 31, ty = threadIdx.x >> 5;  // ty 0..7
#pragma unroll
    for (int r = 0; r < 32; r += 8)
        tile[tx][r + ty] = f2bf(in[(size_t)(bk + r + ty) * N + bn + tx]);
    __syncthreads();
#pragma unroll
    for (int r = 0; r < 32; r += 8)
        out[(size_t)(bn + r + ty) * K + bk + tx] = tile[r + ty][tx];
}

// ---------------- RMSNorm f32 -> bf16 (blocks >= nrows run a f32->bf16 cvt) --------
__global__ __launch_bounds__(256)
void rmsnorm_cvt(const float* __restrict__ x, const float* __restrict__ w,
                 u16* __restrict__ y, int nrows,
                 const float* __restrict__ ca, u16* __restrict__ coa,
                 const float* __restrict__ cb, u16* __restrict__ cob, int n4) {
    int blk = blockIdx.x;
    int t = threadIdx.x;
    if (blk >= nrows) {   // companion cvt slice (dsk/dsv), grid-stride
        int nb = gridDim.x - nrows;
        int stride = nb * 256;
        for (int i = (blk - nrows) * 256 + t; i < 2 * n4; i += stride) {
            const float* in;
            u16* out;
            int j = i;
            if (j < n4) { in = ca; out = coa; }
            else { j -= n4; in = cb; out = cob; }
            float4 v = reinterpret_cast<const float4*>(in)[j];
            uint2 o;
            o.x = pack2(v.x, v.y);
            o.y = pack2(v.z, v.w);
            reinterpret_cast<uint2*>(out)[j] = o;
        }
        return;
    }
    int r = blk;
    const float4* xr = reinterpret_cast<const float4*>(x + (size_t)r * H);
    float4 v0 = xr[t * 2], v1 = xr[t * 2 + 1];
    float ss = v0.x * v0.x + v0.y * v0.y + v0.z * v0.z + v0.w * v0.w
             + v1.x * v1.x + v1.y * v1.y + v1.z * v1.z + v1.w * v1.w;
#pragma unroll
    for (int d = 1; d < 64; d <<= 1) ss += __shfl_xor(ss, d);
    __shared__ float red[4];
    if ((t & 63) == 0) red[t >> 6] = ss;
    __syncthreads();
    float tot = red[0] + red[1] + red[2] + red[3];
    float rs = rsqrtf(tot * (1.0f / H) + 1e-6f);
    const float4* wr = reinterpret_cast<const float4*>(w);
    float4 w0 = wr[t * 2], w1 = wr[t * 2 + 1];
    uint4 o;
    o.x = pack2(v0.x * rs * w0.x, v0.y * rs * w0.y);
    o.y = pack2(v0.z * rs * w0.z, v0.w * rs * w0.w);
    o.z = pack2(v1.x * rs * w1.x, v1.y * rs * w1.y);
    o.w = pack2(v1.z * rs * w1.z, v1.w * rs * w1.w);
    reinterpret_cast<uint4*>(y + (size_t)r * H)[t] = o;
}

// ---------------- GEMM body v3: BK=64, double-buffered, swizzled LDS ----------------
// LDS is caller-provided (single buffer; As = smem[0..16384), Bs = smem[16384..)).
// MODE 0: bf16 C.  MODE 1: Cf = resid + sigmoid(gate)*acc (f32).
template <int MODE, int BN>
__device__ __forceinline__
void gemm_body(u16* __restrict__ smem,
               const u16* __restrict__ A, const u16* __restrict__ Bt,
               u16* __restrict__ Cb, float* __restrict__ Cf,
               const float* __restrict__ resid, const float* __restrict__ gate_p,
               int N, int K, int brow, int bcol) {
    constexpr int WN = BN / 32;          // N frags per wave: 4 or 2
    constexpr int BWROWS = BN / 4;       // B rows staged per wave: 32 or 16
    u16* Asb = smem;                     // 2 x 128*64
    u16* Bsb = smem + 2 * 128 * 64;      // 2 x BN*64
    const int t = threadIdx.x;
    const int lane = t & 63, wid = t >> 6;
    const int wm = wid >> 1, wn = wid & 1;
    const int l15 = lane & 15, hi = lane >> 4;
    const int rsw = l15 & 7;

    f32x4 acc[4][WN] = {};
    const int srow = lane >> 3;
    const int sseg = ((lane & 7) ^ srow) * 8;
    const u16* aBase = A + (size_t)(brow + wid * 32 + srow) * K + sseg;
    const u16* bBase = Bt + (size_t)(bcol + wid * BWROWS + srow) * K + sseg;

#define GSTAGE(KT, BF)                                                          \
    do {                                                                        \
        _Pragma("unroll")                                                       \
        for (int u = 0; u < 4; ++u)                                             \
            GLD_LDS16(aBase + (size_t)(u * 8) * K + (KT),                       \
                      Asb + (BF) * 8192 + (wid * 32 + u * 8) * 64);             \
        _Pragma("unroll")                                                       \
        for (int u = 0; u < BWROWS / 8; ++u)                                    \
            GLD_LDS16(bBase + (size_t)(u * 8) * K + (KT),                       \
                      Bsb + (BF) * (BN * 64) + (wid * BWROWS + u * 8) * 64);    \
    } while (0)

    GSTAGE(0, 0);
    __syncthreads();
    int buf = 0;
    for (int kt = 0; kt < K; kt += 64) {
        if (kt + 64 < K) GSTAGE(kt + 64, buf ^ 1);
        const u16* as = Asb + buf * 8192;
        const u16* bs = Bsb + buf * (BN * 64);
        bf16x8 af[4][2], bfr[WN][2];
#pragma unroll
        for (int i = 0; i < 4; ++i) {
            int row = wm * 64 + i * 16 + l15;
#pragma unroll
            for (int ko = 0; ko < 2; ++ko)
                af[i][ko] = *reinterpret_cast<const bf16x8*>(
                    &as[row * 64 + (((ko * 4 + hi) ^ rsw) * 8)]);
        }
#pragma unroll
        for (int j = 0; j < WN; ++j) {
            int row = wn * (BN / 2) + j * 16 + l15;
#pragma unroll
            for (int ko = 0; ko < 2; ++ko)
                bfr[j][ko] = *reinterpret_cast<const bf16x8*>(
                    &bs[row * 64 + (((ko * 4 + hi) ^ rsw) * 8)]);
        }
#pragma unroll
        for (int ko = 0; ko < 2; ++ko)
#pragma unroll
            for (int i = 0; i < 4; ++i)
#pragma unroll
                for (int j = 0; j < WN; ++j)
                    acc[i][j] = __builtin_amdgcn_mfma_f32_16x16x32_bf16(
                        af[i][ko], bfr[j][ko], acc[i][j], 0, 0, 0);
        __syncthreads();
        buf ^= 1;
    }
#undef GSTAGE

    float g = 0.f;
    if (MODE == 1) g = 1.0f / (1.0f + expf(-gate_p[0]));
    const int r0 = hi * 4, c0 = l15;
#pragma unroll
    for (int i = 0; i < 4; ++i) {
#pragma unroll
        for (int j = 0; j < WN; ++j) {
            int col = bcol + wn * (BN / 2) + j * 16 + c0;
#pragma unroll
            for (int r = 0; r < 4; ++r) {
                int row = brow + wm * 64 + i * 16 + r0 + r;
                float v = acc[i][j][r];
                if (MODE == 0) Cb[(size_t)row * N + col] = f2bf(v);
                else Cf[(size_t)row * N + col] = resid[(size_t)row * N + col] + g * v;
            }
        }
    }
}

template <int MODE, int BN>
__global__ __launch_bounds__(256)
void gemm_tn(const u16* __restrict__ A, const u16* __restrict__ Bt,
             u16* __restrict__ Cb, float* __restrict__ Cf,
             const float* __restrict__ resid, const float* __restrict__ gate_p,
             int M, int N, int K) {
    __shared__ u16 smem[16384 + BN * 128];
    int nbx = gridDim.x;
    int nwg = nbx * gridDim.y;
    int lin = blockIdx.y * nbx + blockIdx.x;
    if (!(nwg & 7)) { int q = nwg >> 3; lin = (lin & 7) * q + (lin >> 3); }
    gemm_body<MODE, BN>(smem, A, Bt, Cb, Cf, resid, gate_p, N, K,
                        (lin / nbx) * 128, (lin % nbx) * BN);
}

// GEMM with a z=1 companion slice running a grid-stride f32->bf16 convert
template <int MODE, int BN>
__global__ __launch_bounds__(256)
void gemm_tn_cvt(const u16* __restrict__ A, const u16* __restrict__ Bt,
                 u16* __restrict__ Cb, float* __restrict__ Cf,
                 const float* __restrict__ resid, const float* __restrict__ gate_p,
                 int M, int N, int K,
                 const float* __restrict__ ca, u16* __restrict__ coa,
                 const float* __restrict__ cb2, u16* __restrict__ cob, int n4) {
    __shared__ u16 smem[16384 + BN * 128];
    if (blockIdx.z == 1) {
        int nblk = gridDim.x * gridDim.y;
        int stride = nblk * 256;
        for (int i = (blockIdx.y * gridDim.x + blockIdx.x) * 256 + threadIdx.x;
             i < 2 * n4; i += stride) {
            const float* in;
            u16* out;
            int j = i;
            if (j < n4) { in = ca; out = coa; }
            else { j -= n4; in = cb2; out = cob; }
            float4 v = reinterpret_cast<const float4*>(in)[j];
            uint2 o;
            o.x = pack2(v.x, v.y);
            o.y = pack2(v.z, v.w);
            reinterpret_cast<uint2*>(out)[j] = o;
        }
        return;
    }
    int nbx = gridDim.x;
    int nwg = nbx * gridDim.y;
    int lin = blockIdx.y * nbx + blockIdx.x;
    if (!(nwg & 7)) { int q = nwg >> 3; lin = (lin & 7) * q + (lin >> 3); }
    gemm_body<MODE, BN>(smem, A, Bt, Cb, Cf, resid, gate_p, N, K,
                        (lin / nbx) * 128, (lin % nbx) * BN);
}

// dual-problem wrapper (kc/vc fused): blockIdx.z selects the pointer set
template <int MODE, int BN>
__global__ __launch_bounds__(256)
void gemm_tn_z2(const u16* __restrict__ A0, const u16* __restrict__ B0, u16* __restrict__ C0,
                const u16* __restrict__ A1, const u16* __restrict__ B1, u16* __restrict__ C1,
                int N, int K) {
    __shared__ u16 smem[16384 + BN * 128];
    const u16* A = blockIdx.z ? A1 : A0;
    const u16* B = blockIdx.z ? B1 : B0;
    u16* C = blockIdx.z ? C1 : C0;
    gemm_body<MODE, BN>(smem, A, B, C, nullptr, nullptr, nullptr, N, K,
                        blockIdx.y * 128, blockIdx.x * BN);
}

// triple co-schedule: fq INTERLEAVED with fk + vT (r18 win: -21us)
__global__ __launch_bounds__(256)
void gemm_triple(const u16* __restrict__ Aq, const u16* __restrict__ Bq,
                 u16* __restrict__ Cq,
                 const u16* __restrict__ Ak, const u16* __restrict__ Bk,
                 u16* __restrict__ Ck,
                 const u16* __restrict__ Av, const u16* __restrict__ Bv,
                 u16* __restrict__ Cv, int K) {
    __shared__ u16 smem[32768];   // 64 KB: max(BN=128 layout)
    int lin = blockIdx.x;         // 0..1023
    if (!(lin & 1)) {
        int l = lin >> 1;         // 0..511, fq: M=4096 N=2048 nbx=16
        int q = 512 >> 3;
        l = (l & 7) * q + (l >> 3);
        gemm_body<0, 128>(smem, Aq, Bq, Cq, nullptr, nullptr, nullptr, 2048, K,
                          (l / 16) * 128, (l % 16) * 128);
    } else {
        int j = lin >> 1;         // 0..511
        if (j < 256) {            // fk: M=4096 N=512 nbx=8
            int q = 256 >> 3;
            j = (j & 7) * q + (j >> 3);
            gemm_body<0, 64>(smem, Ak, Bk, Ck, nullptr, nullptr, nullptr, 512, K,
                             (j / 8) * 128, (j % 8) * 64);
        } else {                  // vT: M=512 N=4096 nbx=64
            j -= 256;
            int q = 256 >> 3;
            j = (j & 7) * q + (j >> 3);
            gemm_body<0, 64>(smem, Av, Bv, Cv, nullptr, nullptr, nullptr, 4096, K,
                             (j / 64) * 128, (j % 64) * 64);
        }
    }
}

// ---------------- coarse attention (ND=64 keys, exact softmax, exp2 domain) --------
__global__ __launch_bounds__(256)
void coarse_attn(const u16* __restrict__ q, const u16* __restrict__ kc,
                 const u16* __restrict__ vc, const float* __restrict__ mask,
                 float* __restrict__ doc_part, u16* __restrict__ attn_c) {
    constexpr int SC = 2048 / 64;
    int bid = blockIdx.x;
    int b = bid / (NH * SC);
    int rem = bid % (NH * SC);
    int h = rem / SC, sc = rem % SC;
    int kv = h >> 2;
    int t = threadIdx.x, lane = t & 63, wid = t >> 6;
    const int l15 = lane & 15, k0 = (lane >> 4) * 8;

    __shared__ u16 Kt[64 * 136];
    __shared__ u16 Vt[128 * 72];
    __shared__ u16 Pt[4][16 * 72];
    __shared__ float p_acc[64];

    {   // stage K [64 keys][128 d]
        int n = t >> 2, s2 = t & 3;
        const u16* src = kc + (size_t)(b * 64 + n) * 512 + kv * 128;
#pragma unroll
        for (int u = 0; u < 4; ++u) {
            int sg = s2 + u * 4;
            *reinterpret_cast<uint4*>(&Kt[n * 136 + sg * 8]) =
                *reinterpret_cast<const uint4*>(src + sg * 8);
        }
    }
    {   // stage V transposed: Vt[d][key]
        int n = t & 63, dblk = t >> 6;
        const u16* src = vc + (size_t)(b * 64 + n) * 512 + kv * 128 + dblk * 32;
#pragma unroll
        for (int u = 0; u < 4; ++u) {
            u16 tmp[8];
            *reinterpret_cast<uint4*>(tmp) = *reinterpret_cast<const uint4*>(src + u * 8);
#pragma unroll
            for (int e = 0; e < 8; ++e) Vt[(dblk * 32 + u * 8 + e) * 72 + n] = tmp[e];
        }
    }
    if (t < 64) p_acc[t] = 0.f;
    __syncthreads();

    int qrow = sc * 64 + wid * 16 + l15;
    const u16* qsrc = q + (size_t)(b * 2048 + qrow) * 2048 + h * 128;
    bf16x8 af[4];
#pragma unroll
    for (int kk = 0; kk < 4; ++kk)
        af[kk] = *reinterpret_cast<const bf16x8*>(qsrc + kk * 32 + k0);

    f32x4 sc4[4] = {};
#pragma unroll
    for (int kk = 0; kk < 4; ++kk)
#pragma unroll
        for (int j = 0; j < 4; ++j) {
            bf16x8 bfr = *reinterpret_cast<const bf16x8*>(&Kt[(j * 16 + l15) * 136 + kk * 32 + k0]);
            sc4[j] = __builtin_amdgcn_mfma_f32_16x16x32_bf16(af[kk], bfr, sc4[j], 0, 0, 0);
        }

    float s[4][4];
#pragma unroll
    for (int j = 0; j < 4; ++j) {
        float bia = (1.0f - mask[b * 64 + j * 16 + l15]) * (-1e9f * L2E);
#pragma unroll
        for (int r = 0; r < 4; ++r) s[j][r] = sc4[j][r] * SCALE2 + bia;
    }
    float m4[4], l4[4];
#pragma unroll
    for (int r = 0; r < 4; ++r) {
        float m = fmaxf(fmaxf(s[0][r], s[1][r]), fmaxf(s[2][r], s[3][r]));
#pragma unroll
        for (int d = 1; d < 16; d <<= 1) m = fmaxf(m, __shfl_xor(m, d));
        m4[r] = m;
    }
#pragma unroll
    for (int r = 0; r < 4; ++r) {
        float l = 0.f;
#pragma unroll
        for (int j = 0; j < 4; ++j) { s[j][r] = exp2f(s[j][r] - m4[r]); l += s[j][r]; }
#pragma unroll
        for (int d = 1; d < 16; d <<= 1) l += __shfl_xor(l, d);
        l4[r] = l;
    }
#pragma unroll
    for (int j = 0; j < 4; ++j) {
        float cs = 0.f;
#pragma unroll
        for (int r = 0; r < 4; ++r) {
            float pr = s[j][r] / l4[r];
            Pt[wid][((lane >> 4) * 4 + r) * 72 + j * 16 + l15] = f2bf(pr);
            cs += pr;
        }
        cs += __shfl_xor(cs, 16);
        cs += __shfl_xor(cs, 32);
        if (lane < 16) atomicAdd(&p_acc[j * 16 + lane], cs);
    }
    __syncthreads();

    f32x4 o4[8] = {};
#pragma unroll
    for (int kk2 = 0; kk2 < 2; ++kk2) {
        bf16x8 a2 = *reinterpret_cast<const bf16x8*>(&Pt[wid][l15 * 72 + kk2 * 32 + k0]);
#pragma unroll
        for (int j2 = 0; j2 < 8; ++j2) {
            bf16x8 b2 = *reinterpret_cast<const bf16x8*>(&Vt[(j2 * 16 + l15) * 72 + kk2 * 32 + k0]);
            o4[j2] = __builtin_amdgcn_mfma_f32_16x16x32_bf16(a2, b2, o4[j2], 0, 0, 0);
        }
    }
#pragma unroll
    for (int j2 = 0; j2 < 8; ++j2)
#pragma unroll
        for (int r = 0; r < 4; ++r) {
            int row = sc * 64 + wid * 16 + (lane >> 4) * 4 + r;
            attn_c[(size_t)(b * 2048 + row) * 2048 + h * 128 + j2 * 16 + l15] = f2bf(o4[j2][r]);
        }
    if (t < 64) atomicAdd(&doc_part[(blockIdx.x & 7) * 128 + b * 64 + t], p_acc[t]);
}

// ---------------- fine bias (doc-score finalize fused; bias pre-scaled by log2e) ----
__global__ __launch_bounds__(256)
void bias_kernel(const float* __restrict__ doc_part, const int* __restrict__ map,
                 const float* __restrict__ tmask, float* __restrict__ bias) {
    __shared__ float lg[128];
    int t = threadIdx.x;
    if (t < 128) {
        float s = 0.f;
#pragma unroll
        for (int i = 0; i < 8; ++i) s += doc_part[i * 128 + t];
        lg[t] = logf(s / 32768.0f + 1e-6f);
    }
    __syncthreads();
    int i = blockIdx.x * 256 + t;
    if (i >= 2 * 2048) return;
    int b = i >> 11;
    bias[i] = (lg[b * 64 + map[i]] + (1.0f - tmask[i]) * -1e9f) * L2E;
}

// ---------------- fine flash attention v7 (r9/r13/r18 version — best measured) ------
__global__ __launch_bounds__(256, 2)
void flash_attn(const u16* __restrict__ q, const u16* __restrict__ kf,
                const u16* __restrict__ vT, const float* __restrict__ bias,
                u16* __restrict__ attn_f) {
    int bid = blockIdx.x;
    int b = bid >> 8;              // NH * 16 = 256 blocks per batch
    int rem = bid & 255;
    int h = rem >> 4, sc = rem & 15;
    int kv = h >> 2;
    int t = threadIdx.x, lane = t & 63, wid = t >> 6;
    const int l15 = lane & 15, hi = lane >> 4;
    const int k0 = hi * 8;
    const int rswp = l15 & 7;

    __shared__ u16 Kt[2][64 * 128];    // [key][d], swizzled 16B slots (32 KB)
    __shared__ u16 Vt[2][128 * 64];    // [d][key], swizzled 16B slots (32 KB)
    __shared__ u16 Pt[4][32 * 64];     // per-wave P[q][key], XOR-swizzled (16 KB)

    bf16x8 qf4[2][4];
#pragma unroll
    for (int f = 0; f < 2; ++f) {
        int qrow = sc * 128 + wid * 32 + f * 16 + l15;
        const u16* qsrc = q + (size_t)(b * 2048 + qrow) * 2048 + h * 128;
#pragma unroll
        for (int kk = 0; kk < 4; ++kk)
            qf4[f][kk] = *reinterpret_cast<const bf16x8*>(qsrc + kk * 32 + k0);
    }

    const int krl = lane >> 4, kslot = lane & 15;   // K: 4 rows x 16 slots per 1KB
    const int vrl = lane >> 3, vslot = lane & 7;    // V: 8 rows x 8 slots per 1KB
    const u16* kbase = kf + (size_t)(b * 2048) * 512 + kv * 128;
    const u16* vbase = vT + (size_t)(kv * 128) * 4096 + b * 2048;
    const float* bbase = bias + b * 2048;

#define STAGE_K(TT, BF)                                                            \
    do {                                                                           \
        _Pragma("unroll")                                                          \
        for (int u = 0; u < 4; ++u) {                                              \
            int row = wid * 16 + u * 4 + krl;                                      \
            const u16* src = kbase + (size_t)((TT) + row) * 512                    \
                             + ((kslot ^ (row & 7)) * 8);                          \
            GLD_LDS16(src, &Kt[BF][(wid * 16 + u * 4) * 128]);                     \
        }                                                                          \
    } while (0)
#define STAGE_V(TT, BF)                                                            \
    do {                                                                           \
        _Pragma("unroll")                                                          \
        for (int u = 0; u < 4; ++u) {                                              \
            int row = wid * 32 + u * 8 + vrl;                                      \
            const u16* src = vbase + (size_t)row * 4096 + (TT)                     \
                             + ((vslot ^ (row & 7)) * 8);                          \
            GLD_LDS16(src, &Vt[BF][(wid * 32 + u * 8) * 64]);                      \
        }                                                                          \
    } while (0)

    float mstate[2] = {-1e30f, -1e30f}, lstate[2] = {0.f, 0.f};   // log2 domain
    f32x4 o4[2][8] = {};

    STAGE_K(0, 0);
    STAGE_V(0, 0);
    __syncthreads();
    int par = 0;

    for (int t0 = 0; t0 < 2048; t0 += 64) {
        int t1 = (t0 + 64) & 2047;          // wrap-around prefetch (last iter harmless)
        STAGE_K(t1, par ^ 1);
        STAGE_V(t1, par ^ 1);

        // QK^T swapped: S^T[key][q]; each K-frag feeds 2 MFMAs
        f32x4 st0[4] = {}, st1[4] = {};
        __builtin_amdgcn_s_setprio(1);
#pragma unroll
        for (int kk = 0; kk < 4; ++kk)
#pragma unroll
            for (int kb = 0; kb < 4; ++kb) {
                int row = kb * 16 + l15;
                bf16x8 kfrag = *reinterpret_cast<const bf16x8*>(
                    &Kt[par][row * 128 + (((kk * 4 + hi) ^ (row & 7)) * 8)]);
                st0[kb] = __builtin_amdgcn_mfma_f32_16x16x32_bf16(kfrag, qf4[0][kk], st0[kb], 0, 0, 0);
                st1[kb] = __builtin_amdgcn_mfma_f32_16x16x32_bf16(kfrag, qf4[1][kk], st1[kb], 0, 0, 0);
            }
        __builtin_amdgcn_s_setprio(0);

        // per-lane: q = f*16 + l15, keys = kb*16 + hi*4 + r ; log2 domain
        float p[2][4][4];
        float pmax[2] = {-1e30f, -1e30f};
#pragma unroll
        for (int kb = 0; kb < 4; ++kb) {
            float4 b4 = *reinterpret_cast<const float4*>(bbase + t0 + kb * 16 + hi * 4);
            float bb[4] = {b4.x, b4.y, b4.z, b4.w};
#pragma unroll
            for (int r = 0; r < 4; ++r) {
                float v0 = st0[kb][r] * SCALE2 + bb[r];
                float v1 = st1[kb][r] * SCALE2 + bb[r];
                p[0][kb][r] = v0;
                p[1][kb][r] = v1;
                pmax[0] = fmaxf(pmax[0], v0);
                pmax[1] = fmaxf(pmax[1], v1);
            }
        }
#pragma unroll
        for (int f = 0; f < 2; ++f) {
            pmax[f] = fmaxf(pmax[f], __shfl_xor(pmax[f], 16));
            pmax[f] = fmaxf(pmax[f], __shfl_xor(pmax[f], 32));
        }

        // defer-max (T13): combined branch; rescale both frags when either needs it
        bool need = (pmax[0] > mstate[0] + THR2) || (pmax[1] > mstate[1] + THR2);
        if (__any(need)) {
#pragma unroll
            for (int f = 0; f < 2; ++f) {
                float mnew = fmaxf(mstate[f], pmax[f]);
                float sco = exp2f(mstate[f] - mnew);
                float sco_out[4];
#pragma unroll
                for (int r = 0; r < 4; ++r) sco_out[r] = __shfl(sco, hi * 4 + r);
#pragma unroll
                for (int j2 = 0; j2 < 8; ++j2)
#pragma unroll
                    for (int r = 0; r < 4; ++r) o4[f][j2][r] *= sco_out[r];
                lstate[f] *= sco;
                mstate[f] = mnew;
            }
        }

#pragma unroll
        for (int f = 0; f < 2; ++f) {
            float lt = 0.f;
#pragma unroll
            for (int kb = 0; kb < 4; ++kb)
#pragma unroll
                for (int r = 0; r < 4; ++r) {
                    p[f][kb][r] = exp2f(p[f][kb][r] - mstate[f]);
                    lt += p[f][kb][r];
                }
            lt += __shfl_xor(lt, 16);
            lt += __shfl_xor(lt, 32);
            lstate[f] += lt;
        }

        // write P[q][key] (per-wave, swizzled b64 writes; same-wave DS ordering)
#pragma unroll
        for (int f = 0; f < 2; ++f)
#pragma unroll
            for (int kb = 0; kb < 4; ++kb) {
                uint2 w;
                w.x = pack2_cvt(p[f][kb][0], p[f][kb][1]);
                w.y = pack2_cvt(p[f][kb][2], p[f][kb][3]);
                int idx = (f * 16 + l15) * 64
                        + (((kb * 2 + (hi >> 1)) ^ rswp) * 8) + (hi & 1) * 4;
                *reinterpret_cast<uint2*>(&Pt[wid][idx]) = w;
            }

        // PV: O[q][d] += P (A) x V^T-frag (B); V-frag feeds 2 MFMAs
        __builtin_amdgcn_s_setprio(1);
#pragma unroll
        for (int kc2 = 0; kc2 < 2; ++kc2) {
            bf16x8 pa0 = *reinterpret_cast<const bf16x8*>(
                &Pt[wid][l15 * 64 + (((kc2 * 4 + hi) ^ rswp) * 8)]);
            bf16x8 pa1 = *reinterpret_cast<const bf16x8*>(
                &Pt[wid][(16 + l15) * 64 + (((kc2 * 4 + hi) ^ rswp) * 8)]);
#pragma unroll
            for (int j2 = 0; j2 < 8; ++j2) {
                int d = j2 * 16 + l15;
                bf16x8 vb = *reinterpret_cast<const bf16x8*>(
                    &Vt[par][d * 64 + (((kc2 * 4 + hi) ^ (d & 7)) * 8)]);
                o4[0][j2] = __builtin_amdgcn_mfma_f32_16x16x32_bf16(pa0, vb, o4[0][j2], 0, 0, 0);
                o4[1][j2] = __builtin_amdgcn_mfma_f32_16x16x32_bf16(pa1, vb, o4[1][j2], 0, 0, 0);
            }
        }
        __builtin_amdgcn_s_setprio(0);
        __syncthreads();   // single drain point: prefetches landed, waves joined
        par ^= 1;
    }
#undef STAGE_K
#undef STAGE_V

    // l is in softmax layout (q = l15 per frag); outputs need q = hi*4+r
#pragma unroll
    for (int f = 0; f < 2; ++f) {
        float linv[4];
#pragma unroll
        for (int r = 0; r < 4; ++r) linv[r] = 1.0f / __shfl(lstate[f], hi * 4 + r);
#pragma unroll
        for (int j2 = 0; j2 < 8; ++j2)
#pragma unroll
            for (int r = 0; r < 4; ++r) {
                int row = sc * 128 + wid * 32 + f * 16 + hi * 4 + r;
                attn_f[(size_t)(b * 2048 + row) * 2048 + h * 128 + j2 * 16 + l15] =
                    f2bf(o4[f][j2][r] * linv[r]);
            }
    }
}

// ---------------- launch ----------------
extern "C" void kernel_launch(void* const* d_in, const int* in_sizes, int n_in,
                              void* d_out, int out_size, void* d_ws, size_t ws_size,
                              hipStream_t stream) {
    const float* hidden = (const float*)d_in[0];
    const float* dsk    = (const float*)d_in[1];
    const float* dsv    = (const float*)d_in[2];
    const float* dsmask = (const float*)d_in[3];
    const float* tk     = (const float*)d_in[4];
    const float* tv     = (const float*)d_in[5];
    const float* tmask  = (const float*)d_in[6];
    const float* cn_w   = (const float*)d_in[7];
    const float* cq_w   = (const float*)d_in[8];
    const float* ck_w   = (const float*)d_in[9];
    const float* cv_w   = (const float*)d_in[10];
    const float* co_w   = (const float*)d_in[11];
    const float* c_gate = (const float*)d_in[12];
    const float* fn_w   = (const float*)d_in[13];
    const float* fq_w   = (const float*)d_in[14];
    const float* fk_w   = (const float*)d_in[15];
    const float* fv_w   = (const float*)d_in[16];
    const float* fo_w   = (const float*)d_in[17];
    const float* f_gate = (const float*)d_in[18];
    const int*   map    = (const int*)d_in[19];
    float* out_f = (float*)d_out;   // also the f32 buffer for coarse residual

    char* ws = (char*)d_ws;
    size_t off = 0;
    auto alloc = [&](size_t bytes) {
        char* p = ws + off;
        off += (bytes + 255) & ~(size_t)255;
        return p;
    };
    u16*  normA = (u16*)alloc(4096ULL * 2048 * 2);
    u16*  qbuf  = (u16*)alloc(4096ULL * 2048 * 2);
    u16*  kc    = (u16*)alloc(128ULL * 512 * 2);
    u16*  vc    = (u16*)alloc(128ULL * 512 * 2);
    u16*  kfb   = (u16*)alloc(4096ULL * 512 * 2);
    u16*  vTb   = (u16*)alloc(512ULL * 4096 * 2);   // V^T [kv*128+d][b*2048+t]
    u16*  tkb   = (u16*)alloc(4096ULL * 2048 * 2);
    u16*  tvb   = (u16*)alloc(4096ULL * 2048 * 2);
    u16*  dskb  = (u16*)alloc(128ULL * 2048 * 2);
    u16*  dsvb  = (u16*)alloc(128ULL * 2048 * 2);
    u16*  cqT   = (u16*)alloc(2048ULL * 2048 * 2);
    u16*  ckT   = (u16*)alloc(512ULL * 2048 * 2);
    u16*  cvT   = (u16*)alloc(512ULL * 2048 * 2);
    u16*  coT   = (u16*)alloc(2048ULL * 2048 * 2);
    u16*  fqT   = (u16*)alloc(2048ULL * 2048 * 2);
    u16*  fkT   = (u16*)alloc(512ULL * 2048 * 2);
    u16*  fvT   = (u16*)alloc(512ULL * 2048 * 2);
    u16*  foT   = (u16*)alloc(2048ULL * 2048 * 2);
    float* doc_part = (float*)alloc(8 * 128 * 4);
    float* biasb    = (float*)alloc(4096 * 4);

    hipMemsetAsync(doc_part, 0, 8 * 128 * 4, stream);

    // weight transposes, batched
    transpose_cvt4<<<dim3(64, 64, 4), 256, 0, stream>>>(cq_w, co_w, fq_w, fo_w,
                                                        cqT, coT, fqT, foT, 2048, 2048);
    transpose_cvt4<<<dim3(16, 64, 4), 256, 0, stream>>>(ck_w, cv_w, fk_w, fv_w,
                                                        ckT, cvT, fkT, fvT, 2048, 512);

    // coarse rmsnorm + co-scheduled dsk/dsv f32->bf16 convert (256 extra blocks)
    rmsnorm_cvt<<<4096 + 256, 256, 0, stream>>>(hidden, cn_w, normA, 4096,
                                                dsk, dskb, dsv, dsvb, 128 * 2048 / 4);

    // coarse q-projection + co-scheduled tk/tv f32->bf16 convert (z=1 slice)
    gemm_tn_cvt<0, 128><<<dim3(16, 32, 2), 256, 0, stream>>>(
        normA, cqT, qbuf, nullptr, nullptr, nullptr, 4096, 2048, 2048,
        tk, tkb, tv, tvb, 4096 * 2048 / 4);
    gemm_tn_z2<0, 64><<<dim3(8, 1, 2), 256, 0, stream>>>(dskb, ckT, kc, dsvb, cvT, vc, 512, 2048);

    // coarse attention (attn_c into normA) + doc-score partials
    coarse_attn<<<1024, 256, 0, stream>>>(qbuf, kc, vc, dsmask, doc_part, normA);
    bias_kernel<<<16, 256, 0, stream>>>(doc_part, map, tmask, biasb);

    // coarse o-proj + residual + gate -> d_out (f32)
    gemm_tn<1, 128><<<dim3(16, 32), 256, 0, stream>>>(normA, coT, nullptr, out_f, hidden, c_gate, 4096, 2048, 2048);

    // fine stage
    rmsnorm_cvt<<<4096, 256, 0, stream>>>(out_f, fn_w, qbuf, 4096,
                                          nullptr, nullptr, nullptr, nullptr, 0);
    // fq + fk + vT co-scheduled (interleaved blocks, shared 64 KB LDS union)
    gemm_triple<<<1024, 256, 0, stream>>>(qbuf, fqT, normA,
                                          tkb, fkT, kfb,
                                          fvT, tvb, vTb, 2048);

    flash_attn<<<512, 256, 0, stream>>>(normA, kfb, vTb, biasb, qbuf);

    // final o-proj + residual + gate -> d_out
    gemm_tn<1, 128><<<dim3(16, 32), 256, 0, stream>>>(qbuf, foT, nullptr, out_f, out_f, f_gate, 4096, 2048, 2048);
}

// Round 21
// 403.355 us; speedup vs baseline: 1.3747x; 1.0340x over previous
//
#include <hip/hip_runtime.h>
#include <hip/hip_bf16.h>

typedef unsigned short u16;
typedef unsigned int u32;
typedef __attribute__((ext_vector_type(8))) short bf16x8;
typedef __attribute__((ext_vector_type(4))) float f32x4;

constexpr int NH = 16;
constexpr int H = 2048;
constexpr float SCALE = 0.08838834764831845f;   // 1/sqrt(128)
constexpr float L2E = 1.4426950408889634f;      // log2(e)
constexpr float SCALE2 = SCALE * L2E;           // QK scale in log2 domain
constexpr float THR2 = 8.0f * L2E;              // defer-max threshold (log2 units)

__device__ __forceinline__ u16 f2bf(float f) {
    u32 u = __float_as_uint(f);
    u32 r = u + 0x7fffu + ((u >> 16) & 1u);   // RNE (finite inputs only)
    return (u16)(r >> 16);
}
__device__ __forceinline__ u32 pack2(float x, float y) {
    return (u32)f2bf(x) | ((u32)f2bf(y) << 16);
}
__device__ __forceinline__ u32 pack2_cvt(float x, float y) {
    __hip_bfloat162 h = __float22bfloat162_rn(float2{x, y});
    return *reinterpret_cast<u32*>(&h);
}

#define GLD_LDS16(gsrc, ldst)                                                  \
    __builtin_amdgcn_global_load_lds(                                          \
        (const __attribute__((address_space(1))) void*)(gsrc),                 \
        (__attribute__((address_space(3))) void*)(ldst), 16, 0, 0)

// ---------------- batched weight transpose + convert: f32[K][N] -> bf16[N][K] -------
__global__ __launch_bounds__(256)
void transpose_cvt4(const float* __restrict__ i0, const float* __restrict__ i1,
                    const float* __restrict__ i2, const float* __restrict__ i3,
                    u16* __restrict__ o0, u16* __restrict__ o1,
                    u16* __restrict__ o2, u16* __restrict__ o3, int K, int N) {
    const float* in = (blockIdx.z == 0) ? i0 : (blockIdx.z == 1) ? i1
                    : (blockIdx.z == 2) ? i2 : i3;
    u16* out = (blockIdx.z == 0) ? o0 : (blockIdx.z == 1) ? o1
             : (blockIdx.z == 2) ? o2 : o3;
    __shared__ u16 tile[32][33];
    int bn = blockIdx.x * 32, bk = blockIdx.y * 32;
    int tx = threadIdx.x & 31, ty = threadIdx.x >> 5;  // ty 0..7
#pragma unroll
    for (int r = 0; r < 32; r += 8)
        tile[tx][r + ty] = f2bf(in[(size_t)(bk + r + ty) * N + bn + tx]);
    __syncthreads();
#pragma unroll
    for (int r = 0; r < 32; r += 8)
        out[(size_t)(bn + r + ty) * K + bk + tx] = tile[r + ty][tx];
}

// ---------------- RMSNorm f32 -> bf16 (blocks >= nrows run a f32->bf16 cvt) --------
__global__ __launch_bounds__(256)
void rmsnorm_cvt(const float* __restrict__ x, const float* __restrict__ w,
                 u16* __restrict__ y, int nrows,
                 const float* __restrict__ ca, u16* __restrict__ coa,
                 const float* __restrict__ cb, u16* __restrict__ cob, int n4) {
    int blk = blockIdx.x;
    int t = threadIdx.x;
    if (blk >= nrows) {   // companion cvt slice (dsk/dsv), grid-stride
        int nb = gridDim.x - nrows;
        int stride = nb * 256;
        for (int i = (blk - nrows) * 256 + t; i < 2 * n4; i += stride) {
            const float* in;
            u16* out;
            int j = i;
            if (j < n4) { in = ca; out = coa; }
            else { j -= n4; in = cb; out = cob; }
            float4 v = reinterpret_cast<const float4*>(in)[j];
            uint2 o;
            o.x = pack2(v.x, v.y);
            o.y = pack2(v.z, v.w);
            reinterpret_cast<uint2*>(out)[j] = o;
        }
        return;
    }
    int r = blk;
    const float4* xr = reinterpret_cast<const float4*>(x + (size_t)r * H);
    float4 v0 = xr[t * 2], v1 = xr[t * 2 + 1];
    float ss = v0.x * v0.x + v0.y * v0.y + v0.z * v0.z + v0.w * v0.w
             + v1.x * v1.x + v1.y * v1.y + v1.z * v1.z + v1.w * v1.w;
#pragma unroll
    for (int d = 1; d < 64; d <<= 1) ss += __shfl_xor(ss, d);
    __shared__ float red[4];
    if ((t & 63) == 0) red[t >> 6] = ss;
    __syncthreads();
    float tot = red[0] + red[1] + red[2] + red[3];
    float rs = rsqrtf(tot * (1.0f / H) + 1e-6f);
    const float4* wr = reinterpret_cast<const float4*>(w);
    float4 w0 = wr[t * 2], w1 = wr[t * 2 + 1];
    uint4 o;
    o.x = pack2(v0.x * rs * w0.x, v0.y * rs * w0.y);
    o.y = pack2(v0.z * rs * w0.z, v0.w * rs * w0.w);
    o.z = pack2(v1.x * rs * w1.x, v1.y * rs * w1.y);
    o.w = pack2(v1.z * rs * w1.z, v1.w * rs * w1.w);
    reinterpret_cast<uint4*>(y + (size_t)r * H)[t] = o;
}

// ---------------- GEMM body v3: BK=64, double-buffered, swizzled LDS ----------------
// LDS is caller-provided (single buffer; As = smem[0..16384), Bs = smem[16384..)).
// MODE 0: bf16 C.  MODE 1: Cf = resid + sigmoid(gate)*acc (f32).
template <int MODE, int BN>
__device__ __forceinline__
void gemm_body(u16* __restrict__ smem,
               const u16* __restrict__ A, const u16* __restrict__ Bt,
               u16* __restrict__ Cb, float* __restrict__ Cf,
               const float* __restrict__ resid, const float* __restrict__ gate_p,
               int N, int K, int brow, int bcol) {
    constexpr int WN = BN / 32;          // N frags per wave: 4 or 2
    constexpr int BWROWS = BN / 4;       // B rows staged per wave: 32 or 16
    u16* Asb = smem;                     // 2 x 128*64
    u16* Bsb = smem + 2 * 128 * 64;      // 2 x BN*64
    const int t = threadIdx.x;
    const int lane = t & 63, wid = t >> 6;
    const int wm = wid >> 1, wn = wid & 1;
    const int l15 = lane & 15, hi = lane >> 4;
    const int rsw = l15 & 7;

    f32x4 acc[4][WN] = {};
    const int srow = lane >> 3;
    const int sseg = ((lane & 7) ^ srow) * 8;
    const u16* aBase = A + (size_t)(brow + wid * 32 + srow) * K + sseg;
    const u16* bBase = Bt + (size_t)(bcol + wid * BWROWS + srow) * K + sseg;

#define GSTAGE(KT, BF)                                                          \
    do {                                                                        \
        _Pragma("unroll")                                                       \
        for (int u = 0; u < 4; ++u)                                             \
            GLD_LDS16(aBase + (size_t)(u * 8) * K + (KT),                       \
                      Asb + (BF) * 8192 + (wid * 32 + u * 8) * 64);             \
        _Pragma("unroll")                                                       \
        for (int u = 0; u < BWROWS / 8; ++u)                                    \
            GLD_LDS16(bBase + (size_t)(u * 8) * K + (KT),                       \
                      Bsb + (BF) * (BN * 64) + (wid * BWROWS + u * 8) * 64);    \
    } while (0)

    GSTAGE(0, 0);
    __syncthreads();
    int buf = 0;
    for (int kt = 0; kt < K; kt += 64) {
        if (kt + 64 < K) GSTAGE(kt + 64, buf ^ 1);
        const u16* as = Asb + buf * 8192;
        const u16* bs = Bsb + buf * (BN * 64);
        bf16x8 af[4][2], bfr[WN][2];
#pragma unroll
        for (int i = 0; i < 4; ++i) {
            int row = wm * 64 + i * 16 + l15;
#pragma unroll
            for (int ko = 0; ko < 2; ++ko)
                af[i][ko] = *reinterpret_cast<const bf16x8*>(
                    &as[row * 64 + (((ko * 4 + hi) ^ rsw) * 8)]);
        }
#pragma unroll
        for (int j = 0; j < WN; ++j) {
            int row = wn * (BN / 2) + j * 16 + l15;
#pragma unroll
            for (int ko = 0; ko < 2; ++ko)
                bfr[j][ko] = *reinterpret_cast<const bf16x8*>(
                    &bs[row * 64 + (((ko * 4 + hi) ^ rsw) * 8)]);
        }
#pragma unroll
        for (int ko = 0; ko < 2; ++ko)
#pragma unroll
            for (int i = 0; i < 4; ++i)
#pragma unroll
                for (int j = 0; j < WN; ++j)
                    acc[i][j] = __builtin_amdgcn_mfma_f32_16x16x32_bf16(
                        af[i][ko], bfr[j][ko], acc[i][j], 0, 0, 0);
        __syncthreads();
        buf ^= 1;
    }
#undef GSTAGE

    float g = 0.f;
    if (MODE == 1) g = 1.0f / (1.0f + expf(-gate_p[0]));
    const int r0 = hi * 4, c0 = l15;
#pragma unroll
    for (int i = 0; i < 4; ++i) {
#pragma unroll
        for (int j = 0; j < WN; ++j) {
            int col = bcol + wn * (BN / 2) + j * 16 + c0;
#pragma unroll
            for (int r = 0; r < 4; ++r) {
                int row = brow + wm * 64 + i * 16 + r0 + r;
                float v = acc[i][j][r];
                if (MODE == 0) Cb[(size_t)row * N + col] = f2bf(v);
                else Cf[(size_t)row * N + col] = resid[(size_t)row * N + col] + g * v;
            }
        }
    }
}

template <int MODE, int BN>
__global__ __launch_bounds__(256)
void gemm_tn(const u16* __restrict__ A, const u16* __restrict__ Bt,
             u16* __restrict__ Cb, float* __restrict__ Cf,
             const float* __restrict__ resid, const float* __restrict__ gate_p,
             int M, int N, int K) {
    __shared__ u16 smem[16384 + BN * 128];
    int nbx = gridDim.x;
    int nwg = nbx * gridDim.y;
    int lin = blockIdx.y * nbx + blockIdx.x;
    if (!(nwg & 7)) { int q = nwg >> 3; lin = (lin & 7) * q + (lin >> 3); }
    gemm_body<MODE, BN>(smem, A, Bt, Cb, Cf, resid, gate_p, N, K,
                        (lin / nbx) * 128, (lin % nbx) * BN);
}

// cq mega-launch: z=0 cq GEMM (512 blocks), z=1 tk/tv cvt (grid-stride),
// z=2 kc/vc thin GEMMs (first 16 blocks; rest exit). All share the hoisted LDS.
template <int MODE, int BN>
__global__ __launch_bounds__(256)
void gemm_tn_mega(const u16* __restrict__ A, const u16* __restrict__ Bt,
                  u16* __restrict__ Cb, float* __restrict__ Cf,
                  const float* __restrict__ resid, const float* __restrict__ gate_p,
                  int M, int N, int K,
                  const float* __restrict__ ca, u16* __restrict__ coa,
                  const float* __restrict__ cb2, u16* __restrict__ cob, int n4,
                  const u16* __restrict__ Ak, const u16* __restrict__ Bk,
                  u16* __restrict__ Ck,
                  const u16* __restrict__ Av, const u16* __restrict__ Bv,
                  u16* __restrict__ Cv) {
    __shared__ u16 smem[16384 + BN * 128];
    if (blockIdx.z == 1) {
        int nblk = gridDim.x * gridDim.y;
        int stride = nblk * 256;
        for (int i = (blockIdx.y * gridDim.x + blockIdx.x) * 256 + threadIdx.x;
             i < 2 * n4; i += stride) {
            const float* in;
            u16* out;
            int j = i;
            if (j < n4) { in = ca; out = coa; }
            else { j -= n4; in = cb2; out = cob; }
            float4 v = reinterpret_cast<const float4*>(in)[j];
            uint2 o;
            o.x = pack2(v.x, v.y);
            o.y = pack2(v.z, v.w);
            reinterpret_cast<uint2*>(out)[j] = o;
        }
        return;
    }
    if (blockIdx.z == 2) {   // kc/vc: M=128, N=512, BN=64 -> 8 blocks each
        int lin = blockIdx.y * gridDim.x + blockIdx.x;
        if (lin < 8)
            gemm_body<0, 64>(smem, Ak, Bk, Ck, nullptr, nullptr, nullptr,
                             512, K, 0, lin * 64);
        else if (lin < 16)
            gemm_body<0, 64>(smem, Av, Bv, Cv, nullptr, nullptr, nullptr,
                             512, K, 0, (lin - 8) * 64);
        return;
    }
    int nbx = gridDim.x;
    int nwg = nbx * gridDim.y;
    int lin = blockIdx.y * nbx + blockIdx.x;
    if (!(nwg & 7)) { int q = nwg >> 3; lin = (lin & 7) * q + (lin >> 3); }
    gemm_body<MODE, BN>(smem, A, Bt, Cb, Cf, resid, gate_p, N, K,
                        (lin / nbx) * 128, (lin % nbx) * BN);
}

// co GEMM with z=1 bias slice (doc-score finalize + fine-bias, 16 real blocks)
template <int MODE, int BN>
__global__ __launch_bounds__(256)
void gemm_tn_bias(const u16* __restrict__ A, const u16* __restrict__ Bt,
                  u16* __restrict__ Cb, float* __restrict__ Cf,
                  const float* __restrict__ resid, const float* __restrict__ gate_p,
                  int M, int N, int K,
                  const float* __restrict__ doc_part, const int* __restrict__ map,
                  const float* __restrict__ tmask, float* __restrict__ bias) {
    __shared__ u16 smem[16384 + BN * 128];
    if (blockIdx.z == 1) {
        int lin = blockIdx.y * gridDim.x + blockIdx.x;
        if (lin >= 16) return;
        __shared__ float lg[128];
        int t = threadIdx.x;
        if (t < 128) {
            float s = 0.f;
#pragma unroll
            for (int i = 0; i < 8; ++i) s += doc_part[i * 128 + t];
            lg[t] = logf(s / 32768.0f + 1e-6f);
        }
        __syncthreads();
        int i = lin * 256 + t;
        if (i < 2 * 2048) {
            int b = i >> 11;
            bias[i] = (lg[b * 64 + map[i]] + (1.0f - tmask[i]) * -1e9f) * L2E;
        }
        return;
    }
    int nbx = gridDim.x;
    int nwg = nbx * gridDim.y;
    int lin = blockIdx.y * nbx + blockIdx.x;
    if (!(nwg & 7)) { int q = nwg >> 3; lin = (lin & 7) * q + (lin >> 3); }
    gemm_body<MODE, BN>(smem, A, Bt, Cb, Cf, resid, gate_p, N, K,
                        (lin / nbx) * 128, (lin % nbx) * BN);
}

// triple co-schedule: fq INTERLEAVED with fk + vT (r18 win: -21us)
__global__ __launch_bounds__(256)
void gemm_triple(const u16* __restrict__ Aq, const u16* __restrict__ Bq,
                 u16* __restrict__ Cq,
                 const u16* __restrict__ Ak, const u16* __restrict__ Bk,
                 u16* __restrict__ Ck,
                 const u16* __restrict__ Av, const u16* __restrict__ Bv,
                 u16* __restrict__ Cv, int K) {
    __shared__ u16 smem[32768];   // 64 KB: max(BN=128 layout)
    int lin = blockIdx.x;         // 0..1023
    if (!(lin & 1)) {
        int l = lin >> 1;         // 0..511, fq: M=4096 N=2048 nbx=16
        int q = 512 >> 3;
        l = (l & 7) * q + (l >> 3);
        gemm_body<0, 128>(smem, Aq, Bq, Cq, nullptr, nullptr, nullptr, 2048, K,
                          (l / 16) * 128, (l % 16) * 128);
    } else {
        int j = lin >> 1;         // 0..511
        if (j < 256) {            // fk: M=4096 N=512 nbx=8
            int q = 256 >> 3;
            j = (j & 7) * q + (j >> 3);
            gemm_body<0, 64>(smem, Ak, Bk, Ck, nullptr, nullptr, nullptr, 512, K,
                             (j / 8) * 128, (j % 8) * 64);
        } else {                  // vT: M=512 N=4096 nbx=64
            j -= 256;
            int q = 256 >> 3;
            j = (j & 7) * q + (j >> 3);
            gemm_body<0, 64>(smem, Av, Bv, Cv, nullptr, nullptr, nullptr, 4096, K,
                             (j / 64) * 128, (j % 64) * 64);
        }
    }
}

// ---------------- coarse attention (ND=64 keys, exact softmax, exp2 domain) --------
__global__ __launch_bounds__(256)
void coarse_attn(const u16* __restrict__ q, const u16* __restrict__ kc,
                 const u16* __restrict__ vc, const float* __restrict__ mask,
                 float* __restrict__ doc_part, u16* __restrict__ attn_c) {
    constexpr int SC = 2048 / 64;
    int bid = blockIdx.x;
    int b = bid / (NH * SC);
    int rem = bid % (NH * SC);
    int h = rem / SC, sc = rem % SC;
    int kv = h >> 2;
    int t = threadIdx.x, lane = t & 63, wid = t >> 6;
    const int l15 = lane & 15, k0 = (lane >> 4) * 8;

    __shared__ u16 Kt[64 * 136];
    __shared__ u16 Vt[128 * 72];
    __shared__ u16 Pt[4][16 * 72];
    __shared__ float p_acc[64];

    {   // stage K [64 keys][128 d]
        int n = t >> 2, s2 = t & 3;
        const u16* src = kc + (size_t)(b * 64 + n) * 512 + kv * 128;
#pragma unroll
        for (int u = 0; u < 4; ++u) {
            int sg = s2 + u * 4;
            *reinterpret_cast<uint4*>(&Kt[n * 136 + sg * 8]) =
                *reinterpret_cast<const uint4*>(src + sg * 8);
        }
    }
    {   // stage V transposed: Vt[d][key]
        int n = t & 63, dblk = t >> 6;
        const u16* src = vc + (size_t)(b * 64 + n) * 512 + kv * 128 + dblk * 32;
#pragma unroll
        for (int u = 0; u < 4; ++u) {
            u16 tmp[8];
            *reinterpret_cast<uint4*>(tmp) = *reinterpret_cast<const uint4*>(src + u * 8);
#pragma unroll
            for (int e = 0; e < 8; ++e) Vt[(dblk * 32 + u * 8 + e) * 72 + n] = tmp[e];
        }
    }
    if (t < 64) p_acc[t] = 0.f;
    __syncthreads();

    int qrow = sc * 64 + wid * 16 + l15;
    const u16* qsrc = q + (size_t)(b * 2048 + qrow) * 2048 + h * 128;
    bf16x8 af[4];
#pragma unroll
    for (int kk = 0; kk < 4; ++kk)
        af[kk] = *reinterpret_cast<const bf16x8*>(qsrc + kk * 32 + k0);

    f32x4 sc4[4] = {};
#pragma unroll
    for (int kk = 0; kk < 4; ++kk)
#pragma unroll
        for (int j = 0; j < 4; ++j) {
            bf16x8 bfr = *reinterpret_cast<const bf16x8*>(&Kt[(j * 16 + l15) * 136 + kk * 32 + k0]);
            sc4[j] = __builtin_amdgcn_mfma_f32_16x16x32_bf16(af[kk], bfr, sc4[j], 0, 0, 0);
        }

    float s[4][4];
#pragma unroll
    for (int j = 0; j < 4; ++j) {
        float bia = (1.0f - mask[b * 64 + j * 16 + l15]) * (-1e9f * L2E);
#pragma unroll
        for (int r = 0; r < 4; ++r) s[j][r] = sc4[j][r] * SCALE2 + bia;
    }
    float m4[4], l4[4];
#pragma unroll
    for (int r = 0; r < 4; ++r) {
        float m = fmaxf(fmaxf(s[0][r], s[1][r]), fmaxf(s[2][r], s[3][r]));
#pragma unroll
        for (int d = 1; d < 16; d <<= 1) m = fmaxf(m, __shfl_xor(m, d));
        m4[r] = m;
    }
#pragma unroll
    for (int r = 0; r < 4; ++r) {
        float l = 0.f;
#pragma unroll
        for (int j = 0; j < 4; ++j) { s[j][r] = exp2f(s[j][r] - m4[r]); l += s[j][r]; }
#pragma unroll
        for (int d = 1; d < 16; d <<= 1) l += __shfl_xor(l, d);
        l4[r] = l;
    }
#pragma unroll
    for (int j = 0; j < 4; ++j) {
        float cs = 0.f;
#pragma unroll
        for (int r = 0; r < 4; ++r) {
            float pr = s[j][r] / l4[r];
            Pt[wid][((lane >> 4) * 4 + r) * 72 + j * 16 + l15] = f2bf(pr);
            cs += pr;
        }
        cs += __shfl_xor(cs, 16);
        cs += __shfl_xor(cs, 32);
        if (lane < 16) atomicAdd(&p_acc[j * 16 + lane], cs);
    }
    __syncthreads();

    f32x4 o4[8] = {};
#pragma unroll
    for (int kk2 = 0; kk2 < 2; ++kk2) {
        bf16x8 a2 = *reinterpret_cast<const bf16x8*>(&Pt[wid][l15 * 72 + kk2 * 32 + k0]);
#pragma unroll
        for (int j2 = 0; j2 < 8; ++j2) {
            bf16x8 b2 = *reinterpret_cast<const bf16x8*>(&Vt[(j2 * 16 + l15) * 72 + kk2 * 32 + k0]);
            o4[j2] = __builtin_amdgcn_mfma_f32_16x16x32_bf16(a2, b2, o4[j2], 0, 0, 0);
        }
    }
#pragma unroll
    for (int j2 = 0; j2 < 8; ++j2)
#pragma unroll
        for (int r = 0; r < 4; ++r) {
            int row = sc * 64 + wid * 16 + (lane >> 4) * 4 + r;
            attn_c[(size_t)(b * 2048 + row) * 2048 + h * 128 + j2 * 16 + l15] = f2bf(o4[j2][r]);
        }
    if (t < 64) atomicAdd(&doc_part[(blockIdx.x & 7) * 128 + b * 64 + t], p_acc[t]);
}

// ---------------- fine flash attention v7 (r9/r13/r18 version — best measured) ------
__global__ __launch_bounds__(256, 2)
void flash_attn(const u16* __restrict__ q, const u16* __restrict__ kf,
                const u16* __restrict__ vT, const float* __restrict__ bias,
                u16* __restrict__ attn_f) {
    int bid = blockIdx.x;
    int b = bid >> 8;              // NH * 16 = 256 blocks per batch
    int rem = bid & 255;
    int h = rem >> 4, sc = rem & 15;
    int kv = h >> 2;
    int t = threadIdx.x, lane = t & 63, wid = t >> 6;
    const int l15 = lane & 15, hi = lane >> 4;
    const int k0 = hi * 8;
    const int rswp = l15 & 7;

    __shared__ u16 Kt[2][64 * 128];    // [key][d], swizzled 16B slots (32 KB)
    __shared__ u16 Vt[2][128 * 64];    // [d][key], swizzled 16B slots (32 KB)
    __shared__ u16 Pt[4][32 * 64];     // per-wave P[q][key], XOR-swizzled (16 KB)

    bf16x8 qf4[2][4];
#pragma unroll
    for (int f = 0; f < 2; ++f) {
        int qrow = sc * 128 + wid * 32 + f * 16 + l15;
        const u16* qsrc = q + (size_t)(b * 2048 + qrow) * 2048 + h * 128;
#pragma unroll
        for (int kk = 0; kk < 4; ++kk)
            qf4[f][kk] = *reinterpret_cast<const bf16x8*>(qsrc + kk * 32 + k0);
    }

    const int krl = lane >> 4, kslot = lane & 15;   // K: 4 rows x 16 slots per 1KB
    const int vrl = lane >> 3, vslot = lane & 7;    // V: 8 rows x 8 slots per 1KB
    const u16* kbase = kf + (size_t)(b * 2048) * 512 + kv * 128;
    const u16* vbase = vT + (size_t)(kv * 128) * 4096 + b * 2048;
    const float* bbase = bias + b * 2048;

#define STAGE_K(TT, BF)                                                            \
    do {                                                                           \
        _Pragma("unroll")                                                          \
        for (int u = 0; u < 4; ++u) {                                              \
            int row = wid * 16 + u * 4 + krl;                                      \
            const u16* src = kbase + (size_t)((TT) + row) * 512                    \
                             + ((kslot ^ (row & 7)) * 8);                          \
            GLD_LDS16(src, &Kt[BF][(wid * 16 + u * 4) * 128]);                     \
        }                                                                          \
    } while (0)
#define STAGE_V(TT, BF)                                                            \
    do {                                                                           \
        _Pragma("unroll")                                                          \
        for (int u = 0; u < 4; ++u) {                                              \
            int row = wid * 32 + u * 8 + vrl;                                      \
            const u16* src = vbase + (size_t)row * 4096 + (TT)                     \
                             + ((vslot ^ (row & 7)) * 8);                          \
            GLD_LDS16(src, &Vt[BF][(wid * 32 + u * 8) * 64]);                      \
        }                                                                          \
    } while (0)

    float mstate[2] = {-1e30f, -1e30f}, lstate[2] = {0.f, 0.f};   // log2 domain
    f32x4 o4[2][8] = {};

    STAGE_K(0, 0);
    STAGE_V(0, 0);
    __syncthreads();
    int par = 0;

    for (int t0 = 0; t0 < 2048; t0 += 64) {
        int t1 = (t0 + 64) & 2047;          // wrap-around prefetch (last iter harmless)
        STAGE_K(t1, par ^ 1);
        STAGE_V(t1, par ^ 1);

        // QK^T swapped: S^T[key][q]; each K-frag feeds 2 MFMAs
        f32x4 st0[4] = {}, st1[4] = {};
        __builtin_amdgcn_s_setprio(1);
#pragma unroll
        for (int kk = 0; kk < 4; ++kk)
#pragma unroll
            for (int kb = 0; kb < 4; ++kb) {
                int row = kb * 16 + l15;
                bf16x8 kfrag = *reinterpret_cast<const bf16x8*>(
                    &Kt[par][row * 128 + (((kk * 4 + hi) ^ (row & 7)) * 8)]);
                st0[kb] = __builtin_amdgcn_mfma_f32_16x16x32_bf16(kfrag, qf4[0][kk], st0[kb], 0, 0, 0);
                st1[kb] = __builtin_amdgcn_mfma_f32_16x16x32_bf16(kfrag, qf4[1][kk], st1[kb], 0, 0, 0);
            }
        __builtin_amdgcn_s_setprio(0);

        // per-lane: q = f*16 + l15, keys = kb*16 + hi*4 + r ; log2 domain
        float p[2][4][4];
        float pmax[2] = {-1e30f, -1e30f};
#pragma unroll
        for (int kb = 0; kb < 4; ++kb) {
            float4 b4 = *reinterpret_cast<const float4*>(bbase + t0 + kb * 16 + hi * 4);
            float bb[4] = {b4.x, b4.y, b4.z, b4.w};
#pragma unroll
            for (int r = 0; r < 4; ++r) {
                float v0 = st0[kb][r] * SCALE2 + bb[r];
                float v1 = st1[kb][r] * SCALE2 + bb[r];
                p[0][kb][r] = v0;
                p[1][kb][r] = v1;
                pmax[0] = fmaxf(pmax[0], v0);
                pmax[1] = fmaxf(pmax[1], v1);
            }
        }
#pragma unroll
        for (int f = 0; f < 2; ++f) {
            pmax[f] = fmaxf(pmax[f], __shfl_xor(pmax[f], 16));
            pmax[f] = fmaxf(pmax[f], __shfl_xor(pmax[f], 32));
        }

        // defer-max (T13): combined branch; rescale both frags when either needs it
        bool need = (pmax[0] > mstate[0] + THR2) || (pmax[1] > mstate[1] + THR2);
        if (__any(need)) {
#pragma unroll
            for (int f = 0; f < 2; ++f) {
                float mnew = fmaxf(mstate[f], pmax[f]);
                float sco = exp2f(mstate[f] - mnew);
                float sco_out[4];
#pragma unroll
                for (int r = 0; r < 4; ++r) sco_out[r] = __shfl(sco, hi * 4 + r);
#pragma unroll
                for (int j2 = 0; j2 < 8; ++j2)
#pragma unroll
                    for (int r = 0; r < 4; ++r) o4[f][j2][r] *= sco_out[r];
                lstate[f] *= sco;
                mstate[f] = mnew;
            }
        }

#pragma unroll
        for (int f = 0; f < 2; ++f) {
            float lt = 0.f;
#pragma unroll
            for (int kb = 0; kb < 4; ++kb)
#pragma unroll
                for (int r = 0; r < 4; ++r) {
                    p[f][kb][r] = exp2f(p[f][kb][r] - mstate[f]);
                    lt += p[f][kb][r];
                }
            lt += __shfl_xor(lt, 16);
            lt += __shfl_xor(lt, 32);
            lstate[f] += lt;
        }

        // write P[q][key] (per-wave, swizzled b64 writes; same-wave DS ordering)
#pragma unroll
        for (int f = 0; f < 2; ++f)
#pragma unroll
            for (int kb = 0; kb < 4; ++kb) {
                uint2 w;
                w.x = pack2_cvt(p[f][kb][0], p[f][kb][1]);
                w.y = pack2_cvt(p[f][kb][2], p[f][kb][3]);
                int idx = (f * 16 + l15) * 64
                        + (((kb * 2 + (hi >> 1)) ^ rswp) * 8) + (hi & 1) * 4;
                *reinterpret_cast<uint2*>(&Pt[wid][idx]) = w;
            }

        // PV: O[q][d] += P (A) x V^T-frag (B); V-frag feeds 2 MFMAs
        __builtin_amdgcn_s_setprio(1);
#pragma unroll
        for (int kc2 = 0; kc2 < 2; ++kc2) {
            bf16x8 pa0 = *reinterpret_cast<const bf16x8*>(
                &Pt[wid][l15 * 64 + (((kc2 * 4 + hi) ^ rswp) * 8)]);
            bf16x8 pa1 = *reinterpret_cast<const bf16x8*>(
                &Pt[wid][(16 + l15) * 64 + (((kc2 * 4 + hi) ^ rswp) * 8)]);
#pragma unroll
            for (int j2 = 0; j2 < 8; ++j2) {
                int d = j2 * 16 + l15;
                bf16x8 vb = *reinterpret_cast<const bf16x8*>(
                    &Vt[par][d * 64 + (((kc2 * 4 + hi) ^ (d & 7)) * 8)]);
                o4[0][j2] = __builtin_amdgcn_mfma_f32_16x16x32_bf16(pa0, vb, o4[0][j2], 0, 0, 0);
                o4[1][j2] = __builtin_amdgcn_mfma_f32_16x16x32_bf16(pa1, vb, o4[1][j2], 0, 0, 0);
            }
        }
        __builtin_amdgcn_s_setprio(0);
        __syncthreads();   // single drain point: prefetches landed, waves joined
        par ^= 1;
    }
#undef STAGE_K
#undef STAGE_V

    // l is in softmax layout (q = l15 per frag); outputs need q = hi*4+r
#pragma unroll
    for (int f = 0; f < 2; ++f) {
        float linv[4];
#pragma unroll
        for (int r = 0; r < 4; ++r) linv[r] = 1.0f / __shfl(lstate[f], hi * 4 + r);
#pragma unroll
        for (int j2 = 0; j2 < 8; ++j2)
#pragma unroll
            for (int r = 0; r < 4; ++r) {
                int row = sc * 128 + wid * 32 + f * 16 + hi * 4 + r;
                attn_f[(size_t)(b * 2048 + row) * 2048 + h * 128 + j2 * 16 + l15] =
                    f2bf(o4[f][j2][r] * linv[r]);
            }
    }
}

// ---------------- launch ----------------
extern "C" void kernel_launch(void* const* d_in, const int* in_sizes, int n_in,
                              void* d_out, int out_size, void* d_ws, size_t ws_size,
                              hipStream_t stream) {
    const float* hidden = (const float*)d_in[0];
    const float* dsk    = (const float*)d_in[1];
    const float* dsv    = (const float*)d_in[2];
    const float* dsmask = (const float*)d_in[3];
    const float* tk     = (const float*)d_in[4];
    const float* tv     = (const float*)d_in[5];
    const float* tmask  = (const float*)d_in[6];
    const float* cn_w   = (const float*)d_in[7];
    const float* cq_w   = (const float*)d_in[8];
    const float* ck_w   = (const float*)d_in[9];
    const float* cv_w   = (const float*)d_in[10];
    const float* co_w   = (const float*)d_in[11];
    const float* c_gate = (const float*)d_in[12];
    const float* fn_w   = (const float*)d_in[13];
    const float* fq_w   = (const float*)d_in[14];
    const float* fk_w   = (const float*)d_in[15];
    const float* fv_w   = (const float*)d_in[16];
    const float* fo_w   = (const float*)d_in[17];
    const float* f_gate = (const float*)d_in[18];
    const int*   map    = (const int*)d_in[19];
    float* out_f = (float*)d_out;   // also the f32 buffer for coarse residual

    char* ws = (char*)d_ws;
    size_t off = 0;
    auto alloc = [&](size_t bytes) {
        char* p = ws + off;
        off += (bytes + 255) & ~(size_t)255;
        return p;
    };
    u16*  normA = (u16*)alloc(4096ULL * 2048 * 2);
    u16*  qbuf  = (u16*)alloc(4096ULL * 2048 * 2);
    u16*  kc    = (u16*)alloc(128ULL * 512 * 2);
    u16*  vc    = (u16*)alloc(128ULL * 512 * 2);
    u16*  kfb   = (u16*)alloc(4096ULL * 512 * 2);
    u16*  vTb   = (u16*)alloc(512ULL * 4096 * 2);   // V^T [kv*128+d][b*2048+t]
    u16*  tkb   = (u16*)alloc(4096ULL * 2048 * 2);
    u16*  tvb   = (u16*)alloc(4096ULL * 2048 * 2);
    u16*  dskb  = (u16*)alloc(128ULL * 2048 * 2);
    u16*  dsvb  = (u16*)alloc(128ULL * 2048 * 2);
    u16*  cqT   = (u16*)alloc(2048ULL * 2048 * 2);
    u16*  ckT   = (u16*)alloc(512ULL * 2048 * 2);
    u16*  cvT   = (u16*)alloc(512ULL * 2048 * 2);
    u16*  coT   = (u16*)alloc(2048ULL * 2048 * 2);
    u16*  fqT   = (u16*)alloc(2048ULL * 2048 * 2);
    u16*  fkT   = (u16*)alloc(512ULL * 2048 * 2);
    u16*  fvT   = (u16*)alloc(512ULL * 2048 * 2);
    u16*  foT   = (u16*)alloc(2048ULL * 2048 * 2);
    float* doc_part = (float*)alloc(8 * 128 * 4);
    float* biasb    = (float*)alloc(4096 * 4);

    hipMemsetAsync(doc_part, 0, 8 * 128 * 4, stream);

    // weight transposes, batched
    transpose_cvt4<<<dim3(64, 64, 4), 256, 0, stream>>>(cq_w, co_w, fq_w, fo_w,
                                                        cqT, coT, fqT, foT, 2048, 2048);
    transpose_cvt4<<<dim3(16, 64, 4), 256, 0, stream>>>(ck_w, cv_w, fk_w, fv_w,
                                                        ckT, cvT, fkT, fvT, 2048, 512);

    // coarse rmsnorm + co-scheduled dsk/dsv f32->bf16 convert (256 extra blocks)
    rmsnorm_cvt<<<4096 + 256, 256, 0, stream>>>(hidden, cn_w, normA, 4096,
                                                dsk, dskb, dsv, dsvb, 128 * 2048 / 4);

    // cq GEMM + tk/tv cvt (z=1) + kc/vc thin GEMMs (z=2), one launch
    gemm_tn_mega<0, 128><<<dim3(16, 32, 3), 256, 0, stream>>>(
        normA, cqT, qbuf, nullptr, nullptr, nullptr, 4096, 2048, 2048,
        tk, tkb, tv, tvb, 4096 * 2048 / 4,
        dskb, ckT, kc, dsvb, cvT, vc);

    // coarse attention (attn_c into normA) + doc-score partials
    coarse_attn<<<1024, 256, 0, stream>>>(qbuf, kc, vc, dsmask, doc_part, normA);

    // coarse o-proj + residual + gate -> d_out (f32), with z=1 bias slice
    gemm_tn_bias<1, 128><<<dim3(16, 32, 2), 256, 0, stream>>>(
        normA, coT, nullptr, out_f, hidden, c_gate, 4096, 2048, 2048,
        doc_part, map, tmask, biasb);

    // fine stage
    rmsnorm_cvt<<<4096, 256, 0, stream>>>(out_f, fn_w, qbuf, 4096,
                                          nullptr, nullptr, nullptr, nullptr, 0);
    // fq + fk + vT co-scheduled (interleaved blocks, shared 64 KB LDS union)
    gemm_triple<<<1024, 256, 0, stream>>>(qbuf, fqT, normA,
                                          tkb, fkT, kfb,
                                          fvT, tvb, vTb, 2048);

    flash_attn<<<512, 256, 0, stream>>>(normA, kfb, vTb, biasb, qbuf);

    // final o-proj + residual + gate -> d_out
    gemm_tn<1, 128><<<dim3(16, 32), 256, 0, stream>>>(qbuf, foT, nullptr, out_f, out_f, f_gate, 4096, 2048, 2048);
}

// Round 22
// 400.502 us; speedup vs baseline: 1.3845x; 1.0071x over previous
//
#include <hip/hip_runtime.h>
#include <hip/hip_bf16.h>

typedef unsigned short u16;
typedef unsigned int u32;
typedef __attribute__((ext_vector_type(8))) short bf16x8;
typedef __attribute__((ext_vector_type(4))) float f32x4;

constexpr int NH = 16;
constexpr int H = 2048;
constexpr float SCALE = 0.08838834764831845f;   // 1/sqrt(128)
constexpr float L2E = 1.4426950408889634f;      // log2(e)
constexpr float SCALE2 = SCALE * L2E;           // QK scale in log2 domain
constexpr float THR2 = 8.0f * L2E;              // defer-max threshold (log2 units)

__device__ __forceinline__ u16 f2bf(float f) {
    u32 u = __float_as_uint(f);
    u32 r = u + 0x7fffu + ((u >> 16) & 1u);   // RNE (finite inputs only)
    return (u16)(r >> 16);
}
__device__ __forceinline__ u32 pack2(float x, float y) {
    return (u32)f2bf(x) | ((u32)f2bf(y) << 16);
}
__device__ __forceinline__ u32 pack2_cvt(float x, float y) {
    __hip_bfloat162 h = __float22bfloat162_rn(float2{x, y});
    return *reinterpret_cast<u32*>(&h);
}

#define GLD_LDS16(gsrc, ldst)                                                  \
    __builtin_amdgcn_global_load_lds(                                          \
        (const __attribute__((address_space(1))) void*)(gsrc),                 \
        (__attribute__((address_space(3))) void*)(ldst), 16, 0, 0)

// ---------------- transpose tile helper: f32[K][N] -> bf16[N][K], 32x32 ----------
__device__ __forceinline__
void transpose_tile(const float* __restrict__ in, u16* __restrict__ out,
                    int K, int N, int bn, int bk, u16 (*tile)[33]) {
    int tx = threadIdx.x & 31, ty = threadIdx.x >> 5;  // ty 0..7
#pragma unroll
    for (int r = 0; r < 32; r += 8)
        tile[tx][r + ty] = f2bf(in[(size_t)(bk + r + ty) * N + bn + tx]);
    __syncthreads();
#pragma unroll
    for (int r = 0; r < 32; r += 8)
        out[(size_t)(bn + r + ty) * K + bk + tx] = tile[r + ty][tx];
}

// ---------------- fused preamble: rmsnorm + dsk/dsv cvt + cq/ck/cv transposes ------
// blocks [0,4096): coarse rmsnorm rows
// blocks [4096,4352): dsk/dsv f32->bf16 (grid-stride over 256 blocks)
// blocks [4352,8448): cq transpose (2048x2048)
// blocks [8448,10496): ck/cv transposes (2048x512 each)
__global__ __launch_bounds__(256)
void preamble(const float* __restrict__ hidden, const float* __restrict__ cn_w,
              u16* __restrict__ normA,
              const float* __restrict__ dsk, u16* __restrict__ dskb,
              const float* __restrict__ dsv, u16* __restrict__ dsvb,
              const float* __restrict__ cq_w, u16* __restrict__ cqT,
              const float* __restrict__ ck_w, u16* __restrict__ ckT,
              const float* __restrict__ cv_w, u16* __restrict__ cvT) {
    __shared__ u16 tile[32][33];
    __shared__ float red[4];
    int blk = blockIdx.x;
    int t = threadIdx.x;
    if (blk < 4096) {   // rmsnorm row
        int r = blk;
        const float4* xr = reinterpret_cast<const float4*>(hidden + (size_t)r * H);
        float4 v0 = xr[t * 2], v1 = xr[t * 2 + 1];
        float ss = v0.x * v0.x + v0.y * v0.y + v0.z * v0.z + v0.w * v0.w
                 + v1.x * v1.x + v1.y * v1.y + v1.z * v1.z + v1.w * v1.w;
#pragma unroll
        for (int d = 1; d < 64; d <<= 1) ss += __shfl_xor(ss, d);
        if ((t & 63) == 0) red[t >> 6] = ss;
        __syncthreads();
        float tot = red[0] + red[1] + red[2] + red[3];
        float rs = rsqrtf(tot * (1.0f / H) + 1e-6f);
        const float4* wr = reinterpret_cast<const float4*>(cn_w);
        float4 w0 = wr[t * 2], w1 = wr[t * 2 + 1];
        uint4 o;
        o.x = pack2(v0.x * rs * w0.x, v0.y * rs * w0.y);
        o.y = pack2(v0.z * rs * w0.z, v0.w * rs * w0.w);
        o.z = pack2(v1.x * rs * w1.x, v1.y * rs * w1.y);
        o.w = pack2(v1.z * rs * w1.z, v1.w * rs * w1.w);
        reinterpret_cast<uint4*>(normA + (size_t)r * H)[t] = o;
        return;
    }
    if (blk < 4352) {   // dsk/dsv cvt, n4 = 65536 per array
        const int n4 = 128 * 2048 / 4;
        int stride = 256 * 256;
        for (int i = (blk - 4096) * 256 + t; i < 2 * n4; i += stride) {
            const float* in;
            u16* out;
            int j = i;
            if (j < n4) { in = dsk; out = dskb; }
            else { j -= n4; in = dsv; out = dsvb; }
            float4 v = reinterpret_cast<const float4*>(in)[j];
            uint2 o;
            o.x = pack2(v.x, v.y);
            o.y = pack2(v.z, v.w);
            reinterpret_cast<uint2*>(out)[j] = o;
        }
        return;
    }
    int r = blk - 4352;
    if (r < 4096) {     // cq: 2048x2048
        transpose_tile(cq_w, cqT, 2048, 2048, (r & 63) * 32, (r >> 6) * 32, tile);
    } else {            // ck/cv: 2048x512
        r -= 4096;
        int m = r >> 10, rr = r & 1023;
        transpose_tile(m ? cv_w : ck_w, m ? cvT : ckT, 2048, 512,
                       (rr & 15) * 32, (rr >> 4) * 32, tile);
    }
}

// ---------------- RMSNorm f32 -> bf16 (fine stage) ----------------
__global__ __launch_bounds__(256)
void rmsnorm_kernel(const float* __restrict__ x, const float* __restrict__ w,
                    u16* __restrict__ y) {
    int r = blockIdx.x;
    int t = threadIdx.x;
    const float4* xr = reinterpret_cast<const float4*>(x + (size_t)r * H);
    float4 v0 = xr[t * 2], v1 = xr[t * 2 + 1];
    float ss = v0.x * v0.x + v0.y * v0.y + v0.z * v0.z + v0.w * v0.w
             + v1.x * v1.x + v1.y * v1.y + v1.z * v1.z + v1.w * v1.w;
#pragma unroll
    for (int d = 1; d < 64; d <<= 1) ss += __shfl_xor(ss, d);
    __shared__ float red[4];
    if ((t & 63) == 0) red[t >> 6] = ss;
    __syncthreads();
    float tot = red[0] + red[1] + red[2] + red[3];
    float rs = rsqrtf(tot * (1.0f / H) + 1e-6f);
    const float4* wr = reinterpret_cast<const float4*>(w);
    float4 w0 = wr[t * 2], w1 = wr[t * 2 + 1];
    uint4 o;
    o.x = pack2(v0.x * rs * w0.x, v0.y * rs * w0.y);
    o.y = pack2(v0.z * rs * w0.z, v0.w * rs * w0.w);
    o.z = pack2(v1.x * rs * w1.x, v1.y * rs * w1.y);
    o.w = pack2(v1.z * rs * w1.z, v1.w * rs * w1.w);
    reinterpret_cast<uint4*>(y + (size_t)r * H)[t] = o;
}

// ---------------- GEMM body v3: BK=64, double-buffered, swizzled LDS ----------------
// LDS is caller-provided. MODE 0: bf16 C. MODE 1: Cf = resid + sigmoid(gate)*acc.
template <int MODE, int BN>
__device__ __forceinline__
void gemm_body(u16* __restrict__ smem,
               const u16* __restrict__ A, const u16* __restrict__ Bt,
               u16* __restrict__ Cb, float* __restrict__ Cf,
               const float* __restrict__ resid, const float* __restrict__ gate_p,
               int N, int K, int brow, int bcol) {
    constexpr int WN = BN / 32;          // N frags per wave: 4 or 2
    constexpr int BWROWS = BN / 4;       // B rows staged per wave: 32 or 16
    u16* Asb = smem;                     // 2 x 128*64
    u16* Bsb = smem + 2 * 128 * 64;      // 2 x BN*64
    const int t = threadIdx.x;
    const int lane = t & 63, wid = t >> 6;
    const int wm = wid >> 1, wn = wid & 1;
    const int l15 = lane & 15, hi = lane >> 4;
    const int rsw = l15 & 7;

    f32x4 acc[4][WN] = {};
    const int srow = lane >> 3;
    const int sseg = ((lane & 7) ^ srow) * 8;
    const u16* aBase = A + (size_t)(brow + wid * 32 + srow) * K + sseg;
    const u16* bBase = Bt + (size_t)(bcol + wid * BWROWS + srow) * K + sseg;

#define GSTAGE(KT, BF)                                                          \
    do {                                                                        \
        _Pragma("unroll")                                                       \
        for (int u = 0; u < 4; ++u)                                             \
            GLD_LDS16(aBase + (size_t)(u * 8) * K + (KT),                       \
                      Asb + (BF) * 8192 + (wid * 32 + u * 8) * 64);             \
        _Pragma("unroll")                                                       \
        for (int u = 0; u < BWROWS / 8; ++u)                                    \
            GLD_LDS16(bBase + (size_t)(u * 8) * K + (KT),                       \
                      Bsb + (BF) * (BN * 64) + (wid * BWROWS + u * 8) * 64);    \
    } while (0)

    GSTAGE(0, 0);
    __syncthreads();
    int buf = 0;
    for (int kt = 0; kt < K; kt += 64) {
        if (kt + 64 < K) GSTAGE(kt + 64, buf ^ 1);
        const u16* as = Asb + buf * 8192;
        const u16* bs = Bsb + buf * (BN * 64);
        bf16x8 af[4][2], bfr[WN][2];
#pragma unroll
        for (int i = 0; i < 4; ++i) {
            int row = wm * 64 + i * 16 + l15;
#pragma unroll
            for (int ko = 0; ko < 2; ++ko)
                af[i][ko] = *reinterpret_cast<const bf16x8*>(
                    &as[row * 64 + (((ko * 4 + hi) ^ rsw) * 8)]);
        }
#pragma unroll
        for (int j = 0; j < WN; ++j) {
            int row = wn * (BN / 2) + j * 16 + l15;
#pragma unroll
            for (int ko = 0; ko < 2; ++ko)
                bfr[j][ko] = *reinterpret_cast<const bf16x8*>(
                    &bs[row * 64 + (((ko * 4 + hi) ^ rsw) * 8)]);
        }
#pragma unroll
        for (int ko = 0; ko < 2; ++ko)
#pragma unroll
            for (int i = 0; i < 4; ++i)
#pragma unroll
                for (int j = 0; j < WN; ++j)
                    acc[i][j] = __builtin_amdgcn_mfma_f32_16x16x32_bf16(
                        af[i][ko], bfr[j][ko], acc[i][j], 0, 0, 0);
        __syncthreads();
        buf ^= 1;
    }
#undef GSTAGE

    float g = 0.f;
    if (MODE == 1) g = 1.0f / (1.0f + expf(-gate_p[0]));
    const int r0 = hi * 4, c0 = l15;
#pragma unroll
    for (int i = 0; i < 4; ++i) {
#pragma unroll
        for (int j = 0; j < WN; ++j) {
            int col = bcol + wn * (BN / 2) + j * 16 + c0;
#pragma unroll
            for (int r = 0; r < 4; ++r) {
                int row = brow + wm * 64 + i * 16 + r0 + r;
                float v = acc[i][j][r];
                if (MODE == 0) Cb[(size_t)row * N + col] = f2bf(v);
                else Cf[(size_t)row * N + col] = resid[(size_t)row * N + col] + g * v;
            }
        }
    }
}

template <int MODE, int BN>
__global__ __launch_bounds__(256)
void gemm_tn(const u16* __restrict__ A, const u16* __restrict__ Bt,
             u16* __restrict__ Cb, float* __restrict__ Cf,
             const float* __restrict__ resid, const float* __restrict__ gate_p,
             int M, int N, int K) {
    __shared__ u16 smem[16384 + BN * 128];
    int nbx = gridDim.x;
    int nwg = nbx * gridDim.y;
    int lin = blockIdx.y * nbx + blockIdx.x;
    if (!(nwg & 7)) { int q = nwg >> 3; lin = (lin & 7) * q + (lin >> 3); }
    gemm_body<MODE, BN>(smem, A, Bt, Cb, Cf, resid, gate_p, N, K,
                        (lin / nbx) * 128, (lin % nbx) * BN);
}

// cq mega-launch: z=0 cq GEMM (512 blocks), z=1 tk/tv cvt (grid-stride),
// z=2 kc/vc thin GEMMs (first 16 blocks; rest exit). All share the hoisted LDS.
template <int MODE, int BN>
__global__ __launch_bounds__(256)
void gemm_tn_mega(const u16* __restrict__ A, const u16* __restrict__ Bt,
                  u16* __restrict__ Cb, float* __restrict__ Cf,
                  const float* __restrict__ resid, const float* __restrict__ gate_p,
                  int M, int N, int K,
                  const float* __restrict__ ca, u16* __restrict__ coa,
                  const float* __restrict__ cb2, u16* __restrict__ cob, int n4,
                  const u16* __restrict__ Ak, const u16* __restrict__ Bk,
                  u16* __restrict__ Ck,
                  const u16* __restrict__ Av, const u16* __restrict__ Bv,
                  u16* __restrict__ Cv) {
    __shared__ u16 smem[16384 + BN * 128];
    if (blockIdx.z == 1) {
        int nblk = gridDim.x * gridDim.y;
        int stride = nblk * 256;
        for (int i = (blockIdx.y * gridDim.x + blockIdx.x) * 256 + threadIdx.x;
             i < 2 * n4; i += stride) {
            const float* in;
            u16* out;
            int j = i;
            if (j < n4) { in = ca; out = coa; }
            else { j -= n4; in = cb2; out = cob; }
            float4 v = reinterpret_cast<const float4*>(in)[j];
            uint2 o;
            o.x = pack2(v.x, v.y);
            o.y = pack2(v.z, v.w);
            reinterpret_cast<uint2*>(out)[j] = o;
        }
        return;
    }
    if (blockIdx.z == 2) {   // kc/vc: M=128, N=512, BN=64 -> 8 blocks each
        int lin = blockIdx.y * gridDim.x + blockIdx.x;
        if (lin < 8)
            gemm_body<0, 64>(smem, Ak, Bk, Ck, nullptr, nullptr, nullptr,
                             512, K, 0, lin * 64);
        else if (lin < 16)
            gemm_body<0, 64>(smem, Av, Bv, Cv, nullptr, nullptr, nullptr,
                             512, K, 0, (lin - 8) * 64);
        return;
    }
    int nbx = gridDim.x;
    int nwg = nbx * gridDim.y;
    int lin = blockIdx.y * nbx + blockIdx.x;
    if (!(nwg & 7)) { int q = nwg >> 3; lin = (lin & 7) * q + (lin >> 3); }
    gemm_body<MODE, BN>(smem, A, Bt, Cb, Cf, resid, gate_p, N, K,
                        (lin / nbx) * 128, (lin % nbx) * BN);
}

// co GEMM with z=1 bias slice (doc-score finalize + fine-bias, 16 real blocks)
template <int MODE, int BN>
__global__ __launch_bounds__(256)
void gemm_tn_bias(const u16* __restrict__ A, const u16* __restrict__ Bt,
                  u16* __restrict__ Cb, float* __restrict__ Cf,
                  const float* __restrict__ resid, const float* __restrict__ gate_p,
                  int M, int N, int K,
                  const float* __restrict__ doc_part, const int* __restrict__ map,
                  const float* __restrict__ tmask, float* __restrict__ bias) {
    __shared__ u16 smem[16384 + BN * 128];
    if (blockIdx.z == 1) {
        int lin = blockIdx.y * gridDim.x + blockIdx.x;
        if (lin >= 16) return;
        __shared__ float lg[128];
        int t = threadIdx.x;
        if (t < 128) {
            float s = 0.f;
#pragma unroll
            for (int i = 0; i < 8; ++i) s += doc_part[i * 128 + t];
            lg[t] = logf(s / 32768.0f + 1e-6f);
        }
        __syncthreads();
        int i = lin * 256 + t;
        if (i < 2 * 2048) {
            int b = i >> 11;
            bias[i] = (lg[b * 64 + map[i]] + (1.0f - tmask[i]) * -1e9f) * L2E;
        }
        return;
    }
    int nbx = gridDim.x;
    int nwg = nbx * gridDim.y;
    int lin = blockIdx.y * nbx + blockIdx.x;
    if (!(nwg & 7)) { int q = nwg >> 3; lin = (lin & 7) * q + (lin >> 3); }
    gemm_body<MODE, BN>(smem, A, Bt, Cb, Cf, resid, gate_p, N, K,
                        (lin / nbx) * 128, (lin % nbx) * BN);
}

// triple co-schedule: fq INTERLEAVED with fk + vT (r18 win: -21us)
__global__ __launch_bounds__(256)
void gemm_triple(const u16* __restrict__ Aq, const u16* __restrict__ Bq,
                 u16* __restrict__ Cq,
                 const u16* __restrict__ Ak, const u16* __restrict__ Bk,
                 u16* __restrict__ Ck,
                 const u16* __restrict__ Av, const u16* __restrict__ Bv,
                 u16* __restrict__ Cv, int K) {
    __shared__ u16 smem[32768];   // 64 KB: max(BN=128 layout)
    int lin = blockIdx.x;         // 0..1023
    if (!(lin & 1)) {
        int l = lin >> 1;         // 0..511, fq: M=4096 N=2048 nbx=16
        int q = 512 >> 3;
        l = (l & 7) * q + (l >> 3);
        gemm_body<0, 128>(smem, Aq, Bq, Cq, nullptr, nullptr, nullptr, 2048, K,
                          (l / 16) * 128, (l % 16) * 128);
    } else {
        int j = lin >> 1;         // 0..511
        if (j < 256) {            // fk: M=4096 N=512 nbx=8
            int q = 256 >> 3;
            j = (j & 7) * q + (j >> 3);
            gemm_body<0, 64>(smem, Ak, Bk, Ck, nullptr, nullptr, nullptr, 512, K,
                             (j / 8) * 128, (j % 8) * 64);
        } else {                  // vT: M=512 N=4096 nbx=64
            j -= 256;
            int q = 256 >> 3;
            j = (j & 7) * q + (j >> 3);
            gemm_body<0, 64>(smem, Av, Bv, Cv, nullptr, nullptr, nullptr, 4096, K,
                             (j / 64) * 128, (j % 64) * 64);
        }
    }
}

// ---------------- coarse attention + deferred fine-weight transposes ----------------
// blocks [0,1024): attention.  blocks [1024,15360): transposes of coT/fqT/foT
// (2048x2048, 4096 blocks each) and fkT/fvT (2048x512, 1024 each), consumed by
// later launches. LDS statics sum to ~47.4 KB -> 3 blocks/CU (unchanged).
__global__ __launch_bounds__(256)
void coarse_attn_tr(const u16* __restrict__ q, const u16* __restrict__ kc,
                    const u16* __restrict__ vc, const float* __restrict__ mask,
                    float* __restrict__ doc_part, u16* __restrict__ attn_c,
                    const float* __restrict__ co_w, u16* __restrict__ coT,
                    const float* __restrict__ fq_w, u16* __restrict__ fqT,
                    const float* __restrict__ fo_w, u16* __restrict__ foT,
                    const float* __restrict__ fk_w, u16* __restrict__ fkT,
                    const float* __restrict__ fv_w, u16* __restrict__ fvT) {
    __shared__ u16 tile[32][33];
    int bid = blockIdx.x;
    if (bid >= 1024) {
        int r = bid - 1024;
        if (r < 12288) {   // co/fq/fo: 2048x2048
            int m = r / 4096, rr = r % 4096;
            const float* in = (m == 0) ? co_w : (m == 1) ? fq_w : fo_w;
            u16* out = (m == 0) ? coT : (m == 1) ? fqT : foT;
            transpose_tile(in, out, 2048, 2048, (rr & 63) * 32, (rr >> 6) * 32, tile);
        } else {           // fk/fv: 2048x512
            int r2 = r - 12288;
            int m = r2 >> 10, rr = r2 & 1023;
            transpose_tile(m ? fv_w : fk_w, m ? fvT : fkT, 2048, 512,
                           (rr & 15) * 32, (rr >> 4) * 32, tile);
        }
        return;
    }
    constexpr int SC = 2048 / 64;
    int b = bid / (NH * SC);
    int rem = bid % (NH * SC);
    int h = rem / SC, sc = rem % SC;
    int kv = h >> 2;
    int t = threadIdx.x, lane = t & 63, wid = t >> 6;
    const int l15 = lane & 15, k0 = (lane >> 4) * 8;

    __shared__ u16 Kt[64 * 136];
    __shared__ u16 Vt[128 * 72];
    __shared__ u16 Pt[4][16 * 72];
    __shared__ float p_acc[64];

    {   // stage K [64 keys][128 d]
        int n = t >> 2, s2 = t & 3;
        const u16* src = kc + (size_t)(b * 64 + n) * 512 + kv * 128;
#pragma unroll
        for (int u = 0; u < 4; ++u) {
            int sg = s2 + u * 4;
            *reinterpret_cast<uint4*>(&Kt[n * 136 + sg * 8]) =
                *reinterpret_cast<const uint4*>(src + sg * 8);
        }
    }
    {   // stage V transposed: Vt[d][key]
        int n = t & 63, dblk = t >> 6;
        const u16* src = vc + (size_t)(b * 64 + n) * 512 + kv * 128 + dblk * 32;
#pragma unroll
        for (int u = 0; u < 4; ++u) {
            u16 tmp[8];
            *reinterpret_cast<uint4*>(tmp) = *reinterpret_cast<const uint4*>(src + u * 8);
#pragma unroll
            for (int e = 0; e < 8; ++e) Vt[(dblk * 32 + u * 8 + e) * 72 + n] = tmp[e];
        }
    }
    if (t < 64) p_acc[t] = 0.f;
    __syncthreads();

    int qrow = sc * 64 + wid * 16 + l15;
    const u16* qsrc = q + (size_t)(b * 2048 + qrow) * 2048 + h * 128;
    bf16x8 af[4];
#pragma unroll
    for (int kk = 0; kk < 4; ++kk)
        af[kk] = *reinterpret_cast<const bf16x8*>(qsrc + kk * 32 + k0);

    f32x4 sc4[4] = {};
#pragma unroll
    for (int kk = 0; kk < 4; ++kk)
#pragma unroll
        for (int j = 0; j < 4; ++j) {
            bf16x8 bfr = *reinterpret_cast<const bf16x8*>(&Kt[(j * 16 + l15) * 136 + kk * 32 + k0]);
            sc4[j] = __builtin_amdgcn_mfma_f32_16x16x32_bf16(af[kk], bfr, sc4[j], 0, 0, 0);
        }

    float s[4][4];
#pragma unroll
    for (int j = 0; j < 4; ++j) {
        float bia = (1.0f - mask[b * 64 + j * 16 + l15]) * (-1e9f * L2E);
#pragma unroll
        for (int r = 0; r < 4; ++r) s[j][r] = sc4[j][r] * SCALE2 + bia;
    }
    float m4[4], l4[4];
#pragma unroll
    for (int r = 0; r < 4; ++r) {
        float m = fmaxf(fmaxf(s[0][r], s[1][r]), fmaxf(s[2][r], s[3][r]));
#pragma unroll
        for (int d = 1; d < 16; d <<= 1) m = fmaxf(m, __shfl_xor(m, d));
        m4[r] = m;
    }
#pragma unroll
    for (int r = 0; r < 4; ++r) {
        float l = 0.f;
#pragma unroll
        for (int j = 0; j < 4; ++j) { s[j][r] = exp2f(s[j][r] - m4[r]); l += s[j][r]; }
#pragma unroll
        for (int d = 1; d < 16; d <<= 1) l += __shfl_xor(l, d);
        l4[r] = l;
    }
#pragma unroll
    for (int j = 0; j < 4; ++j) {
        float cs = 0.f;
#pragma unroll
        for (int r = 0; r < 4; ++r) {
            float pr = s[j][r] / l4[r];
            Pt[wid][((lane >> 4) * 4 + r) * 72 + j * 16 + l15] = f2bf(pr);
            cs += pr;
        }
        cs += __shfl_xor(cs, 16);
        cs += __shfl_xor(cs, 32);
        if (lane < 16) atomicAdd(&p_acc[j * 16 + lane], cs);
    }
    __syncthreads();

    f32x4 o4[8] = {};
#pragma unroll
    for (int kk2 = 0; kk2 < 2; ++kk2) {
        bf16x8 a2 = *reinterpret_cast<const bf16x8*>(&Pt[wid][l15 * 72 + kk2 * 32 + k0]);
#pragma unroll
        for (int j2 = 0; j2 < 8; ++j2) {
            bf16x8 b2 = *reinterpret_cast<const bf16x8*>(&Vt[(j2 * 16 + l15) * 72 + kk2 * 32 + k0]);
            o4[j2] = __builtin_amdgcn_mfma_f32_16x16x32_bf16(a2, b2, o4[j2], 0, 0, 0);
        }
    }
#pragma unroll
    for (int j2 = 0; j2 < 8; ++j2)
#pragma unroll
        for (int r = 0; r < 4; ++r) {
            int row = sc * 64 + wid * 16 + (lane >> 4) * 4 + r;
            attn_c[(size_t)(b * 2048 + row) * 2048 + h * 128 + j2 * 16 + l15] = f2bf(o4[j2][r]);
        }
    if (t < 64) atomicAdd(&doc_part[(bid & 7) * 128 + b * 64 + t], p_acc[t]);
}

// ---------------- fine flash attention v7 (r9/r13/r18 version — best measured) ------
__global__ __launch_bounds__(256, 2)
void flash_attn(const u16* __restrict__ q, const u16* __restrict__ kf,
                const u16* __restrict__ vT, const float* __restrict__ bias,
                u16* __restrict__ attn_f) {
    int bid = blockIdx.x;
    int b = bid >> 8;              // NH * 16 = 256 blocks per batch
    int rem = bid & 255;
    int h = rem >> 4, sc = rem & 15;
    int kv = h >> 2;
    int t = threadIdx.x, lane = t & 63, wid = t >> 6;
    const int l15 = lane & 15, hi = lane >> 4;
    const int k0 = hi * 8;
    const int rswp = l15 & 7;

    __shared__ u16 Kt[2][64 * 128];    // [key][d], swizzled 16B slots (32 KB)
    __shared__ u16 Vt[2][128 * 64];    // [d][key], swizzled 16B slots (32 KB)
    __shared__ u16 Pt[4][32 * 64];     // per-wave P[q][key], XOR-swizzled (16 KB)

    bf16x8 qf4[2][4];
#pragma unroll
    for (int f = 0; f < 2; ++f) {
        int qrow = sc * 128 + wid * 32 + f * 16 + l15;
        const u16* qsrc = q + (size_t)(b * 2048 + qrow) * 2048 + h * 128;
#pragma unroll
        for (int kk = 0; kk < 4; ++kk)
            qf4[f][kk] = *reinterpret_cast<const bf16x8*>(qsrc + kk * 32 + k0);
    }

    const int krl = lane >> 4, kslot = lane & 15;   // K: 4 rows x 16 slots per 1KB
    const int vrl = lane >> 3, vslot = lane & 7;    // V: 8 rows x 8 slots per 1KB
    const u16* kbase = kf + (size_t)(b * 2048) * 512 + kv * 128;
    const u16* vbase = vT + (size_t)(kv * 128) * 4096 + b * 2048;
    const float* bbase = bias + b * 2048;

#define STAGE_K(TT, BF)                                                            \
    do {                                                                           \
        _Pragma("unroll")                                                          \
        for (int u = 0; u < 4; ++u) {                                              \
            int row = wid * 16 + u * 4 + krl;                                      \
            const u16* src = kbase + (size_t)((TT) + row) * 512                    \
                             + ((kslot ^ (row & 7)) * 8);                          \
            GLD_LDS16(src, &Kt[BF][(wid * 16 + u * 4) * 128]);                     \
        }                                                                          \
    } while (0)
#define STAGE_V(TT, BF)                                                            \
    do {                                                                           \
        _Pragma("unroll")                                                          \
        for (int u = 0; u < 4; ++u) {                                              \
            int row = wid * 32 + u * 8 + vrl;                                      \
            const u16* src = vbase + (size_t)row * 4096 + (TT)                     \
                             + ((vslot ^ (row & 7)) * 8);                          \
            GLD_LDS16(src, &Vt[BF][(wid * 32 + u * 8) * 64]);                      \
        }                                                                          \
    } while (0)

    float mstate[2] = {-1e30f, -1e30f}, lstate[2] = {0.f, 0.f};   // log2 domain
    f32x4 o4[2][8] = {};

    STAGE_K(0, 0);
    STAGE_V(0, 0);
    __syncthreads();
    int par = 0;

    for (int t0 = 0; t0 < 2048; t0 += 64) {
        int t1 = (t0 + 64) & 2047;          // wrap-around prefetch (last iter harmless)
        STAGE_K(t1, par ^ 1);
        STAGE_V(t1, par ^ 1);

        // QK^T swapped: S^T[key][q]; each K-frag feeds 2 MFMAs
        f32x4 st0[4] = {}, st1[4] = {};
        __builtin_amdgcn_s_setprio(1);
#pragma unroll
        for (int kk = 0; kk < 4; ++kk)
#pragma unroll
            for (int kb = 0; kb < 4; ++kb) {
                int row = kb * 16 + l15;
                bf16x8 kfrag = *reinterpret_cast<const bf16x8*>(
                    &Kt[par][row * 128 + (((kk * 4 + hi) ^ (row & 7)) * 8)]);
                st0[kb] = __builtin_amdgcn_mfma_f32_16x16x32_bf16(kfrag, qf4[0][kk], st0[kb], 0, 0, 0);
                st1[kb] = __builtin_amdgcn_mfma_f32_16x16x32_bf16(kfrag, qf4[1][kk], st1[kb], 0, 0, 0);
            }
        __builtin_amdgcn_s_setprio(0);

        // per-lane: q = f*16 + l15, keys = kb*16 + hi*4 + r ; log2 domain
        float p[2][4][4];
        float pmax[2] = {-1e30f, -1e30f};
#pragma unroll
        for (int kb = 0; kb < 4; ++kb) {
            float4 b4 = *reinterpret_cast<const float4*>(bbase + t0 + kb * 16 + hi * 4);
            float bb[4] = {b4.x, b4.y, b4.z, b4.w};
#pragma unroll
            for (int r = 0; r < 4; ++r) {
                float v0 = st0[kb][r] * SCALE2 + bb[r];
                float v1 = st1[kb][r] * SCALE2 + bb[r];
                p[0][kb][r] = v0;
                p[1][kb][r] = v1;
                pmax[0] = fmaxf(pmax[0], v0);
                pmax[1] = fmaxf(pmax[1], v1);
            }
        }
#pragma unroll
        for (int f = 0; f < 2; ++f) {
            pmax[f] = fmaxf(pmax[f], __shfl_xor(pmax[f], 16));
            pmax[f] = fmaxf(pmax[f], __shfl_xor(pmax[f], 32));
        }

        // defer-max (T13): combined branch; rescale both frags when either needs it
        bool need = (pmax[0] > mstate[0] + THR2) || (pmax[1] > mstate[1] + THR2);
        if (__any(need)) {
#pragma unroll
            for (int f = 0; f < 2; ++f) {
                float mnew = fmaxf(mstate[f], pmax[f]);
                float sco = exp2f(mstate[f] - mnew);
                float sco_out[4];
#pragma unroll
                for (int r = 0; r < 4; ++r) sco_out[r] = __shfl(sco, hi * 4 + r);
#pragma unroll
                for (int j2 = 0; j2 < 8; ++j2)
#pragma unroll
                    for (int r = 0; r < 4; ++r) o4[f][j2][r] *= sco_out[r];
                lstate[f] *= sco;
                mstate[f] = mnew;
            }
        }

#pragma unroll
        for (int f = 0; f < 2; ++f) {
            float lt = 0.f;
#pragma unroll
            for (int kb = 0; kb < 4; ++kb)
#pragma unroll
                for (int r = 0; r < 4; ++r) {
                    p[f][kb][r] = exp2f(p[f][kb][r] - mstate[f]);
                    lt += p[f][kb][r];
                }
            lt += __shfl_xor(lt, 16);
            lt += __shfl_xor(lt, 32);
            lstate[f] += lt;
        }

        // write P[q][key] (per-wave, swizzled b64 writes; same-wave DS ordering)
#pragma unroll
        for (int f = 0; f < 2; ++f)
#pragma unroll
            for (int kb = 0; kb < 4; ++kb) {
                uint2 w;
                w.x = pack2_cvt(p[f][kb][0], p[f][kb][1]);
                w.y = pack2_cvt(p[f][kb][2], p[f][kb][3]);
                int idx = (f * 16 + l15) * 64
                        + (((kb * 2 + (hi >> 1)) ^ rswp) * 8) + (hi & 1) * 4;
                *reinterpret_cast<uint2*>(&Pt[wid][idx]) = w;
            }

        // PV: O[q][d] += P (A) x V^T-frag (B); V-frag feeds 2 MFMAs
        __builtin_amdgcn_s_setprio(1);
#pragma unroll
        for (int kc2 = 0; kc2 < 2; ++kc2) {
            bf16x8 pa0 = *reinterpret_cast<const bf16x8*>(
                &Pt[wid][l15 * 64 + (((kc2 * 4 + hi) ^ rswp) * 8)]);
            bf16x8 pa1 = *reinterpret_cast<const bf16x8*>(
                &Pt[wid][(16 + l15) * 64 + (((kc2 * 4 + hi) ^ rswp) * 8)]);
#pragma unroll
            for (int j2 = 0; j2 < 8; ++j2) {
                int d = j2 * 16 + l15;
                bf16x8 vb = *reinterpret_cast<const bf16x8*>(
                    &Vt[par][d * 64 + (((kc2 * 4 + hi) ^ (d & 7)) * 8)]);
                o4[0][j2] = __builtin_amdgcn_mfma_f32_16x16x32_bf16(pa0, vb, o4[0][j2], 0, 0, 0);
                o4[1][j2] = __builtin_amdgcn_mfma_f32_16x16x32_bf16(pa1, vb, o4[1][j2], 0, 0, 0);
            }
        }
        __builtin_amdgcn_s_setprio(0);
        __syncthreads();   // single drain point: prefetches landed, waves joined
        par ^= 1;
    }
#undef STAGE_K
#undef STAGE_V

    // l is in softmax layout (q = l15 per frag); outputs need q = hi*4+r
#pragma unroll
    for (int f = 0; f < 2; ++f) {
        float linv[4];
#pragma unroll
        for (int r = 0; r < 4; ++r) linv[r] = 1.0f / __shfl(lstate[f], hi * 4 + r);
#pragma unroll
        for (int j2 = 0; j2 < 8; ++j2)
#pragma unroll
            for (int r = 0; r < 4; ++r) {
                int row = sc * 128 + wid * 32 + f * 16 + hi * 4 + r;
                attn_f[(size_t)(b * 2048 + row) * 2048 + h * 128 + j2 * 16 + l15] =
                    f2bf(o4[f][j2][r] * linv[r]);
            }
    }
}

// ---------------- launch ----------------
extern "C" void kernel_launch(void* const* d_in, const int* in_sizes, int n_in,
                              void* d_out, int out_size, void* d_ws, size_t ws_size,
                              hipStream_t stream) {
    const float* hidden = (const float*)d_in[0];
    const float* dsk    = (const float*)d_in[1];
    const float* dsv    = (const float*)d_in[2];
    const float* dsmask = (const float*)d_in[3];
    const float* tk     = (const float*)d_in[4];
    const float* tv     = (const float*)d_in[5];
    const float* tmask  = (const float*)d_in[6];
    const float* cn_w   = (const float*)d_in[7];
    const float* cq_w   = (const float*)d_in[8];
    const float* ck_w   = (const float*)d_in[9];
    const float* cv_w   = (const float*)d_in[10];
    const float* co_w   = (const float*)d_in[11];
    const float* c_gate = (const float*)d_in[12];
    const float* fn_w   = (const float*)d_in[13];
    const float* fq_w   = (const float*)d_in[14];
    const float* fk_w   = (const float*)d_in[15];
    const float* fv_w   = (const float*)d_in[16];
    const float* fo_w   = (const float*)d_in[17];
    const float* f_gate = (const float*)d_in[18];
    const int*   map    = (const int*)d_in[19];
    float* out_f = (float*)d_out;   // also the f32 buffer for coarse residual

    char* ws = (char*)d_ws;
    size_t off = 0;
    auto alloc = [&](size_t bytes) {
        char* p = ws + off;
        off += (bytes + 255) & ~(size_t)255;
        return p;
    };
    u16*  normA = (u16*)alloc(4096ULL * 2048 * 2);
    u16*  qbuf  = (u16*)alloc(4096ULL * 2048 * 2);
    u16*  kc    = (u16*)alloc(128ULL * 512 * 2);
    u16*  vc    = (u16*)alloc(128ULL * 512 * 2);
    u16*  kfb   = (u16*)alloc(4096ULL * 512 * 2);
    u16*  vTb   = (u16*)alloc(512ULL * 4096 * 2);   // V^T [kv*128+d][b*2048+t]
    u16*  tkb   = (u16*)alloc(4096ULL * 2048 * 2);
    u16*  tvb   = (u16*)alloc(4096ULL * 2048 * 2);
    u16*  dskb  = (u16*)alloc(128ULL * 2048 * 2);
    u16*  dsvb  = (u16*)alloc(128ULL * 2048 * 2);
    u16*  cqT   = (u16*)alloc(2048ULL * 2048 * 2);
    u16*  ckT   = (u16*)alloc(512ULL * 2048 * 2);
    u16*  cvT   = (u16*)alloc(512ULL * 2048 * 2);
    u16*  coT   = (u16*)alloc(2048ULL * 2048 * 2);
    u16*  fqT   = (u16*)alloc(2048ULL * 2048 * 2);
    u16*  fkT   = (u16*)alloc(512ULL * 2048 * 2);
    u16*  fvT   = (u16*)alloc(512ULL * 2048 * 2);
    u16*  foT   = (u16*)alloc(2048ULL * 2048 * 2);
    float* doc_part = (float*)alloc(8 * 128 * 4);
    float* biasb    = (float*)alloc(4096 * 4);

    hipMemsetAsync(doc_part, 0, 8 * 128 * 4, stream);

    // fused preamble: coarse rmsnorm + dsk/dsv cvt + cq/ck/cv transposes
    preamble<<<10496, 256, 0, stream>>>(hidden, cn_w, normA,
                                        dsk, dskb, dsv, dsvb,
                                        cq_w, cqT, ck_w, ckT, cv_w, cvT);

    // cq GEMM + tk/tv cvt (z=1) + kc/vc thin GEMMs (z=2), one launch
    gemm_tn_mega<0, 128><<<dim3(16, 32, 3), 256, 0, stream>>>(
        normA, cqT, qbuf, nullptr, nullptr, nullptr, 4096, 2048, 2048,
        tk, tkb, tv, tvb, 4096 * 2048 / 4,
        dskb, ckT, kc, dsvb, cvT, vc);

    // coarse attention + deferred fine-weight transposes (one launch)
    coarse_attn_tr<<<15360, 256, 0, stream>>>(qbuf, kc, vc, dsmask, doc_part, normA,
                                              co_w, coT, fq_w, fqT, fo_w, foT,
                                              fk_w, fkT, fv_w, fvT);

    // coarse o-proj + residual + gate -> d_out (f32), with z=1 bias slice
    gemm_tn_bias<1, 128><<<dim3(16, 32, 2), 256, 0, stream>>>(
        normA, coT, nullptr, out_f, hidden, c_gate, 4096, 2048, 2048,
        doc_part, map, tmask, biasb);

    // fine stage
    rmsnorm_kernel<<<4096, 256, 0, stream>>>(out_f, fn_w, qbuf);
    // fq + fk + vT co-scheduled (interleaved blocks, shared 64 KB LDS union)
    gemm_triple<<<1024, 256, 0, stream>>>(qbuf, fqT, normA,
                                          tkb, fkT, kfb,
                                          fvT, tvb, vTb, 2048);

    flash_attn<<<512, 256, 0, stream>>>(normA, kfb, vTb, biasb, qbuf);

    // final o-proj + residual + gate -> d_out
    gemm_tn<1, 128><<<dim3(16, 32), 256, 0, stream>>>(qbuf, foT, nullptr, out_f, out_f, f_gate, 4096, 2048, 2048);
}